// Round 6
// baseline (1328.290 us; speedup 1.0000x reference)
//
#include <hip/hip_runtime.h>
#include <math.h>

#define TPB 256

__device__ __forceinline__ float lrelu(float x){ return x > 0.f ? x : 0.2f*x; }

// ---------------- CSR build (graph constant across layers) ----------------
__global__ void k_init_cnt(int* __restrict__ cnt, int N){
  int t = blockIdx.x*TPB + threadIdx.x;
  if (t < 4*N) cnt[t] = (t < 3*N) ? 1 : 0;  // GAT counts start at 1 (self-loop)
}

__global__ void k_count(const int* __restrict__ ei, int* __restrict__ cnt, int N, int E){
  int t = blockIdx.x*TPB + threadIdx.x;
  if (t >= 3*E) return;
  int r = t / E, e = t - r*E;
  int dst = ei[(r*2+1)*E + e];
  atomicAdd(&cnt[r*N + dst], 1);
  atomicAdd(&cnt[3*N + dst], 1);
}

// scan + cursor init fused
__global__ void k_scan4(const int* __restrict__ cnt, int* __restrict__ rp,
                        int* __restrict__ cur, int N){
  __shared__ int sh[1024];
  __shared__ int carry;
  int a = blockIdx.x;
  const int* c = cnt + a*N;
  int* r = rp + a*(N+1);
  if (threadIdx.x == 0) carry = 0;
  __syncthreads();
  for (int base = 0; base < N; base += 1024){
    int idx = base + threadIdx.x;
    int v = (idx < N) ? c[idx] : 0;
    sh[threadIdx.x] = v;
    __syncthreads();
    for (int off = 1; off < 1024; off <<= 1){
      int t = (threadIdx.x >= off) ? sh[threadIdx.x - off] : 0;
      __syncthreads();
      sh[threadIdx.x] += t;
      __syncthreads();
    }
    if (idx < N){
      int ex = carry + sh[threadIdx.x] - v;   // exclusive
      r[idx] = ex;
      cur[a*N + idx] = ex;
    }
    __syncthreads();
    if (threadIdx.x == 0) carry += sh[1023];
    __syncthreads();
  }
  if (threadIdx.x == 0) r[N] = carry;
}

__global__ void k_scatter(const int* __restrict__ ei, int* __restrict__ cur,
                          int* __restrict__ idx_gat,
                          int* __restrict__ idx_hgt, int* __restrict__ idx_hgt_dst,
                          int N, int E){
  int t = blockIdx.x*TPB + threadIdx.x;
  int EN = E + N;
  if (t < 3*E){
    int r = t / E, e = t - r*E;
    int src = ei[(r*2)*E + e];
    int dst = ei[(r*2+1)*E + e];
    int pg = atomicAdd(&cur[r*N + dst], 1);
    idx_gat[r*EN + pg] = src;
    int ph = atomicAdd(&cur[3*N + dst], 1);
    idx_hgt[ph] = r*N + src;           // packed (rel,src)
    idx_hgt_dst[ph] = dst;
  } else if (t < 3*E + 3*N){
    int tt = t - 3*E;
    int r = tt / N, i = tt - r*N;
    int pg = atomicAdd(&cur[r*N + i], 1);
    idx_gat[r*EN + pg] = i;            // self loop
  }
}

// ---------------- LDS-tiled dense GEMM + optional fused GAT att-dots ----------------
// A:[n,K]; W:[nmat,K,96]; C:[nmat,n,96]. Block = 192 threads -> 96x96 tile, 6x8/thread.
// If att != nullptr (GAT): also emit asrc/adst[mat*n + row][head] from raw acc (pre-bias).
#define GTPB 192
__global__ __launch_bounds__(GTPB) void k_gemm_t(const float* __restrict__ A,
                        const float* __restrict__ W,
                        const float* __restrict__ bias, float* __restrict__ C,
                        int n, int K, const float* __restrict__ att,
                        float* __restrict__ asrc, float* __restrict__ adst){
  __shared__ float Wl[96*96];
  __shared__ float red[96][4];
  int mat = blockIdx.y;
  const float4* Wm4 = reinterpret_cast<const float4*>(W + (size_t)mat*K*96);
  for (int idx = threadIdx.x; idx < K*24; idx += GTPB)
    reinterpret_cast<float4*>(Wl)[idx] = Wm4[idx];
  __syncthreads();

  int cg = threadIdx.x % 12;
  int rg = threadIdx.x / 12;     // 0..15
  int c0 = cg*8;
  int r0 = blockIdx.x*96 + rg*6;

  float acc[6][8];
  #pragma unroll
  for (int u = 0; u < 6; u++)
    #pragma unroll
    for (int c = 0; c < 8; c++) acc[u][c] = 0.f;

  for (int k = 0; k < K; k += 4){
    float4 a[6];
    #pragma unroll
    for (int u = 0; u < 6; u++){
      int r = r0 + u;
      a[u] = (r < n) ? *reinterpret_cast<const float4*>(A + (size_t)r*K + k)
                     : make_float4(0.f,0.f,0.f,0.f);
    }
    #pragma unroll
    for (int kk = 0; kk < 4; kk++){
      float4 w0 = *reinterpret_cast<const float4*>(Wl + (k+kk)*96 + c0);
      float4 w1 = *reinterpret_cast<const float4*>(Wl + (k+kk)*96 + c0 + 4);
      float wv0 = w0.x, wv1 = w0.y, wv2 = w0.z, wv3 = w0.w;
      float wv4 = w1.x, wv5 = w1.y, wv6 = w1.z, wv7 = w1.w;
      #pragma unroll
      for (int u = 0; u < 6; u++){
        float av = (kk==0) ? a[u].x : (kk==1) ? a[u].y : (kk==2) ? a[u].z : a[u].w;
        acc[u][0] += av*wv0; acc[u][1] += av*wv1; acc[u][2] += av*wv2; acc[u][3] += av*wv3;
        acc[u][4] += av*wv4; acc[u][5] += av*wv5; acc[u][6] += av*wv6; acc[u][7] += av*wv7;
      }
    }
  }

  if (att){   // fused GAT attention dots (uses raw acc; GAT gemm has bias=nullptr)
    for (int z = threadIdx.x; z < 96*4; z += GTPB) (&red[0][0])[z] = 0.f;
    __syncthreads();
    const float* ap = att + mat*192;     // [2,2,48] per relation
    int hh = c0 / 48;                    // this thread's 8 cols lie in one head
    #pragma unroll
    for (int u = 0; u < 6; u++){
      float sp = 0.f, dp = 0.f;
      #pragma unroll
      for (int j = 0; j < 8; j++){
        sp += acc[u][j] * ap[c0 + j];
        dp += acc[u][j] * ap[96 + c0 + j];
      }
      atomicAdd(&red[rg*6 + u][hh*2],     sp);
      atomicAdd(&red[rg*6 + u][hh*2 + 1], dp);
    }
    __syncthreads();
    int tid = threadIdx.x;
    if (tid < 192){
      int row = tid >> 1, h = tid & 1;
      int grow = blockIdx.x*96 + row;
      if (grow < n){
        asrc[((size_t)mat*n + grow)*2 + h] = red[row][h*2];
        adst[((size_t)mat*n + grow)*2 + h] = red[row][h*2 + 1];
      }
    }
  }

  float b[8];
  if (bias){
    const float* bp = bias + mat*96 + c0;
    #pragma unroll
    for (int c = 0; c < 8; c++) b[c] = bp[c];
  } else {
    #pragma unroll
    for (int c = 0; c < 8; c++) b[c] = 0.f;
  }
  #pragma unroll
  for (int u = 0; u < 6; u++){
    int r = r0 + u;
    if (r < n){
      float* Cr = C + (size_t)mat*n*96 + (size_t)r*96 + c0;
      float4 o0 = make_float4(acc[u][0]+b[0], acc[u][1]+b[1], acc[u][2]+b[2], acc[u][3]+b[3]);
      float4 o1 = make_float4(acc[u][4]+b[4], acc[u][5]+b[5], acc[u][6]+b[6], acc[u][7]+b[7]);
      reinterpret_cast<float4*>(Cr)[0] = o0;
      reinterpret_cast<float4*>(Cr)[1] = o1;
    }
  }
}

// ---------------- HGT effective-weight prep: fold a_rel/m_rel/p_rel into kqv weights ----
// Wbig[7][96][96]: mat0=q, mat1..3=K_r (scaled by 0.25*p_rel), mat4..6=V_r. bbig[7][96].
__global__ void k_prep(const float* __restrict__ kW, const float* __restrict__ kb,
                       const float* __restrict__ arel, const float* __restrict__ mrel,
                       const float* __restrict__ prel,
                       float* __restrict__ Wbig, float* __restrict__ bbig){
  int t = blockIdx.x*TPB + threadIdx.x;
  const int total = 7*96*96;
  if (t < total){
    int m = t / (96*96);
    int rem = t - m*(96*96);
    int c = rem / 96;
    int o = rem - c*96;
    float val;
    if (m == 0){
      val = kW[(size_t)96*96 + c*96 + o];            // q weights
    } else {
      int r = (m - 1) % 3;
      bool isV = m >= 4;
      const float* base = isV ? mrel : arel;         // [3][6][16][16]
      const float* wsrc = kW + (size_t)(isV ? 2 : 0)*96*96;
      int h = o >> 4, ff = o & 15;
      float s = 0.f;
      #pragma unroll
      for (int d = 0; d < 16; d++)
        s += wsrc[c*96 + h*16 + d] * base[(size_t)((r*6 + h)*16 + d)*16 + ff];
      if (!isV) s *= 0.25f * prel[r*6 + h];
      val = s;
    }
    Wbig[t] = val;
  } else if (t < total + 7*96){
    int tt = t - total;
    int m = tt / 96, o = tt - m*96;
    float val;
    if (m == 0){
      val = kb[96 + o];
    } else {
      int r = (m - 1) % 3;
      bool isV = m >= 4;
      const float* base = isV ? mrel : arel;
      const float* bsrc = kb + (isV ? 2 : 0)*96;
      int h = o >> 4, ff = o & 15;
      float s = 0.f;
      #pragma unroll
      for (int d = 0; d < 16; d++)
        s += bsrc[h*16 + d] * base[(size_t)((r*6 + h)*16 + d)*16 + ff];
      if (!isV) s *= 0.25f * prel[r*6 + h];
      val = s;
    }
    bbig[tt] = val;
  }
}

// ---------------- GAT fused: wave per node; weights + gather + combine + bias + BN stats ----
__global__ __launch_bounds__(TPB) void k_gat_fused(const float* __restrict__ asrc,
                        const float* __restrict__ adst, const float* __restrict__ hp,
                        const int* __restrict__ rowptr, const int* __restrict__ idxg,
                        const float* __restrict__ b3, float* __restrict__ pre,
                        float* __restrict__ stats, int n, int EN){
  __shared__ float s1[96], s2[96];
  if (threadIdx.x < 96){ s1[threadIdx.x] = 0.f; s2[threadIdx.x] = 0.f; }
  __syncthreads();
  int wid = (blockIdx.x*TPB + threadIdx.x) >> 6;   // wave id = node
  int lane = threadIdx.x & 63;
  if (wid < n){
    float comb_a = 0.f, comb_b = 0.f;
    #pragma unroll
    for (int r = 0; r < 3; r++){
      const int* rp = rowptr + r*(n+1);
      int s0 = rp[wid], s1e = rp[wid+1];
      const int* ix = idxg + (size_t)r*EN;
      const float2* as2 = reinterpret_cast<const float2*>(asrc) + (size_t)r*n;
      float2 ad = (reinterpret_cast<const float2*>(adst) + (size_t)r*n)[wid];
      const float* hpb = hp + (size_t)r*n*96;
      float acc_a = 0.f, acc_b = 0.f, ss0 = 0.f, ss1 = 0.f;
      for (int base = s0; base < s1e; base += 64){
        int cnt = min(64, s1e - base);
        int src_l = 0; float w0_l = 0.f, w1_l = 0.f;
        if (lane < cnt){
          src_l = ix[base + lane];
          float2 av = as2[src_l];
          w0_l = __expf(fminf(lrelu(av.x + ad.x), 80.f));
          w1_l = __expf(fminf(lrelu(av.y + ad.y), 80.f));
        }
        for (int j = 0; j < cnt; j++){
          int   src = __shfl(src_l, j);
          float w0  = __shfl(w0_l, j);
          float w1  = __shfl(w1_l, j);
          const float* row = hpb + (size_t)src*96;
          float va = row[lane];
          float vb = (lane < 32) ? row[64 + lane] : 0.f;
          float wa = (lane < 48) ? w0 : w1;
          acc_a += wa*va;
          acc_b += w1*vb;
          ss0 += w0; ss1 += w1;
        }
      }
      comb_a += acc_a / ((lane < 48) ? ss0 : ss1);   // self-loop => non-empty
      comb_b += acc_b / ss1;
    }
    comb_a += b3[lane] + b3[96 + lane] + b3[192 + lane];
    float* pr = pre + (size_t)wid*96;
    pr[lane] = comb_a;
    atomicAdd(&s1[lane], comb_a);
    atomicAdd(&s2[lane], comb_a*comb_a);
    if (lane < 32){
      comb_b += b3[64 + lane] + b3[160 + lane] + b3[256 + lane];
      pr[64 + lane] = comb_b;
      atomicAdd(&s1[64 + lane], comb_b);
      atomicAdd(&s2[64 + lane], comb_b*comb_b);
    }
  }
  __syncthreads();
  if (threadIdx.x < 96){
    atomicAdd(&stats[threadIdx.x], s1[threadIdx.x]);
    atomicAdd(&stats[96 + threadIdx.x], s2[threadIdx.x]);
  }
}

// ---------------- HGT skip-mix in place + BN stats ----------------
__global__ void k_mix_stats(float* __restrict__ pre, const float* __restrict__ h,
                            const float* __restrict__ skip, float* __restrict__ stats, int total){
  __shared__ float s1[96], s2[96];
  if (threadIdx.x < 96){ s1[threadIdx.x] = 0.f; s2[threadIdx.x] = 0.f; }
  __syncthreads();
  float sk = 1.f / (1.f + expf(-skip[0]));
  int idx0 = blockIdx.x*TPB*8 + threadIdx.x;
  for (int it = 0; it < 8; it++){
    int idx = idx0 + it*TPB;
    if (idx < total){
      int c = idx % 96;
      float v = sk*pre[idx] + (1.f - sk)*h[idx];
      pre[idx] = v;
      atomicAdd(&s1[c], v);
      atomicAdd(&s2[c], v*v);
    }
  }
  __syncthreads();
  if (threadIdx.x < 96){
    atomicAdd(&stats[threadIdx.x], s1[threadIdx.x]);
    atomicAdd(&stats[96 + threadIdx.x], s2[threadIdx.x]);
  }
}

// ---------------- apply with inline BN finalize: h = lrelu(res*h + bn(pre) + inj) ----------------
__global__ void k_apply2(float* __restrict__ h, const float* __restrict__ pre,
                         const float* __restrict__ stats, const float* __restrict__ gamma,
                         const float* __restrict__ beta, const float* __restrict__ inj,
                         int res, int total, float inv_n){
  int idx = blockIdx.x*TPB + threadIdx.x;
  if (idx >= total) return;
  int c = idx % 96;
  float mean = stats[c] * inv_n;
  float var  = stats[96 + c] * inv_n - mean*mean;
  float sc   = gamma[c] * rsqrtf(var + 1e-5f);
  float sh   = beta[c] - mean*sc;
  float v = sc*pre[idx] + sh;
  if (inj) v += inj[idx];
  if (res) v += h[idx];
  h[idx] = lrelu(v);
}

// ---------------- HGT phase A: per-(slot,head) edge weights (scale pre-folded) ----------------
__global__ void k_hgt_w(const float* __restrict__ q, const float* __restrict__ Kb,
                        const int* __restrict__ idxh, const int* __restrict__ idxh_dst,
                        float* __restrict__ wbuf, int n, int totE){
  int t = blockIdx.x*TPB + threadIdx.x;
  if (t >= totE*6) return;
  int slot = t / 6, h = t - slot*6;
  int packed = idxh[slot];
  int dst = idxh_dst[slot];
  const float4* kp = reinterpret_cast<const float4*>(Kb + (size_t)packed*96 + h*16);
  const float4* qp = reinterpret_cast<const float4*>(q + (size_t)dst*96 + h*16);
  float dot = 0.f;
  #pragma unroll
  for (int w = 0; w < 4; w++){
    float4 kv = kp[w], qv = qp[w];
    dot += kv.x*qv.x + kv.y*qv.y + kv.z*qv.z + kv.w*qv.w;
  }
  wbuf[t] = __expf(fminf(dot, 80.f));
}

// ---------------- HGT fused gather: wave per node; shfl-staged; + GELU ----------------
__global__ __launch_bounds__(TPB) void k_hgt_fused(const float* __restrict__ wbuf,
                        const float* __restrict__ Vb, const int* __restrict__ rp4,
                        const int* __restrict__ idxh, float* __restrict__ gbuf, int n){
  int wid = (blockIdx.x*TPB + threadIdx.x) >> 6;
  if (wid >= n) return;
  int lane = threadIdx.x & 63;
  const int* rp = rp4 + 3*(n+1);
  int s0 = rp[wid], s1 = rp[wid+1];
  int ha = lane >> 4;                         // head for col=lane (0..3)
  float acc_a = 0.f, acc_b = 0.f, ss_a = 0.f, ss_b = 0.f;
  for (int base = s0; base < s1; base += 64){
    int cnt = min(64, s1 - base);
    int pk = 0; float w0=0.f,w1=0.f,w2=0.f,w3=0.f,w4=0.f,w5=0.f;
    if (lane < cnt){
      int slot = base + lane;
      pk = idxh[slot];
      const float2* wp = reinterpret_cast<const float2*>(wbuf + (size_t)slot*6);
      float2 p0 = wp[0], p1 = wp[1], p2 = wp[2];
      w0=p0.x; w1=p0.y; w2=p1.x; w3=p1.y; w4=p2.x; w5=p2.y;
    }
    for (int j = 0; j < cnt; j++){
      int packed = __shfl(pk, j);
      float b0=__shfl(w0,j), b1=__shfl(w1,j), b2=__shfl(w2,j),
            b3v=__shfl(w3,j), b4=__shfl(w4,j), b5=__shfl(w5,j);
      const float* row = Vb + (size_t)packed*96;
      float va = row[lane];
      float vb = (lane < 32) ? row[64 + lane] : 0.f;
      float wa = (ha==0) ? b0 : ((ha==1) ? b1 : ((ha==2) ? b2 : b3v));
      float wb = ((lane >> 4) == 0) ? b4 : b5;   // head 4/5 for cols 64..95
      acc_a += wa*va; ss_a += wa;
      acc_b += wb*vb; ss_b += wb;
    }
  }
  float xa = (s1 > s0) ? acc_a/ss_a : 0.f;
  float* gb = gbuf + (size_t)wid*96;
  gb[lane] = 0.5f*xa*(1.f + erff(xa*0.70710678118654752f));
  if (lane < 32){
    float xb = (s1 > s0) ? acc_b/ss_b : 0.f;
    gb[64 + lane] = 0.5f*xb*(1.f + erff(xb*0.70710678118654752f));
  }
}

// ---------------- final linear ----------------
__global__ void k_final_lin(const float* __restrict__ h, const float* __restrict__ w,
                            const float* __restrict__ b, float* __restrict__ out, int N){
  int i = blockIdx.x*TPB + threadIdx.x;
  if (i >= N) return;
  const float4* hr = reinterpret_cast<const float4*>(h + (size_t)i*96);
  const float4* wr = reinterpret_cast<const float4*>(w);
  float acc = 0.f;
  #pragma unroll
  for (int c = 0; c < 24; c++){
    float4 a = hr[c], q = wr[c];
    acc += a.x*q.x + a.y*q.y + a.z*q.z + a.w*q.w;
  }
  out[i] = acc + b[0];
}

// =====================================================================
extern "C" void kernel_launch(void* const* d_in, const int* in_sizes, int n_in,
                              void* d_out, int out_size, void* d_ws, size_t ws_size,
                              hipStream_t stream){
  const float* x        = (const float*)d_in[0];
  const int*   ei       = (const int*)  d_in[1];
  const float* gat0_W   = (const float*)d_in[2];
  const float* gat0_att = (const float*)d_in[3];
  const float* gat0_b   = (const float*)d_in[4];
  const float* gat_W    = (const float*)d_in[5];
  const float* gat_att  = (const float*)d_in[6];
  const float* gat_b    = (const float*)d_in[7];
  const float* bn_g     = (const float*)d_in[8];
  const float* bn_b     = (const float*)d_in[9];
  const float* kqv_W    = (const float*)d_in[10];
  const float* kqv_b    = (const float*)d_in[11];
  const float* a_rel    = (const float*)d_in[12];
  const float* m_rel    = (const float*)d_in[13];
  const float* p_rel    = (const float*)d_in[14];
  const float* hout_W   = (const float*)d_in[15];
  const float* hout_b   = (const float*)d_in[16];
  const float* skip     = (const float*)d_in[17];
  const float* proj_W   = (const float*)d_in[18];
  const float* proj_b   = (const float*)d_in[19];
  const float* lin_W    = (const float*)d_in[20];
  const float* lin_b    = (const float*)d_in[21];
  float* out = (float*)d_out;

  const int N = in_sizes[0] / 32;
  const int E = in_sizes[1] / 6;
  const int EN = E + N;
  const size_t NH = (size_t)N * 96;
  const int nh = (int)NH;
  const float inv_n = 1.f / (float)N;

  // ---- workspace layout (floats, then ints) ----
  float* f = (float*)d_ws;
  float* h_buf = f;  f += NH;
  float* pre   = f;  f += NH;        // aliased as wbuf (HGT phase A->B window)
  float* big   = f;  f += 9*NH;      // GAT: hp[3]; HGT: qKV[7] (q,K0..2,V0..2)
  float* aux   = f;  f += NH;        // injection | gelu(agg)
  float* asrc  = f;  f += (size_t)3*N*2;
  float* adst  = f;  f += (size_t)3*N*2;
  float* stats = f;  f += 6*192;     // 6 BN slots of (sum[96], sumsq[96])
  float* Wbig  = f;  f += 7*96*96;
  float* bbig  = f;  f += 7*96;
  int* ip = (int*)f;
  int* cnt     = ip;  ip += 4*N;
  int* rowptr  = ip;  ip += 4*(N+1);
  int* cursor  = ip;  ip += 4*N;
  int* idx_gat     = ip;  ip += 3*EN;
  int* idx_hgt     = ip;  ip += 3*E;
  int* idx_hgt_dst = ip;  ip += 3*E;
  float* wbuf = pre;                 // 3E*6 = 1.8M floats <= NH

  auto g1 = [](int n){ return dim3((n + TPB - 1)/TPB); };
  const int gx = (N + 95)/96;                 // GEMM row-tiles
  const dim3 gg(gx, 3);                       // 3-matrix GEMM grid
  const dim3 gg7(gx, 7);                      // 7-matrix HGT qKV grid
  const dim3 g1m(gx, 1);                      // 1-matrix GEMM grid
  const int cs_blocks = (nh + TPB*8 - 1)/(TPB*8);
  const int wave_blocks = (N + 3)/4;          // 4 waves (nodes) per 256-block

  // ---- CSR build + stats zero ----
  hipMemsetAsync(stats, 0, 6*192*sizeof(float), stream);
  k_init_cnt<<<g1(4*N),     TPB, 0, stream>>>(cnt, N);
  k_count   <<<g1(3*E),     TPB, 0, stream>>>(ei, cnt, N, E);
  k_scan4   <<<4,          1024, 0, stream>>>(cnt, rowptr, cursor, N);
  k_scatter <<<g1(3*E+3*N), TPB, 0, stream>>>(ei, cursor, idx_gat, idx_hgt, idx_hgt_dst, N, E);

  auto run_hgt = [&](int idx, int bnidx){
    k_prep     <<<g1(7*96*96 + 7*96), TPB, 0, stream>>>(
                   kqv_W + (size_t)idx*3*96*96, kqv_b + idx*3*96,
                   a_rel + (size_t)idx*3*6*256, m_rel + (size_t)idx*3*6*256,
                   p_rel + idx*18, Wbig, bbig);
    k_gemm_t   <<<gg7, GTPB, 0, stream>>>(h_buf, Wbig, bbig, big, N, 96,
                                          nullptr, nullptr, nullptr);
    k_hgt_w    <<<g1(3*E*6), TPB, 0, stream>>>(big, big + NH, idx_hgt, idx_hgt_dst, wbuf, N, 3*E);
    k_hgt_fused<<<wave_blocks, TPB, 0, stream>>>(wbuf, big + 4*NH, rowptr, idx_hgt, aux, N);
    k_gemm_t   <<<g1m, GTPB, 0, stream>>>(aux, hout_W + (size_t)idx*96*96, hout_b + idx*96,
                                          pre, N, 96, nullptr, nullptr, nullptr);
    k_mix_stats<<<cs_blocks, TPB, 0, stream>>>(pre, h_buf, skip + idx, stats + bnidx*192, nh);
    k_apply2   <<<g1(nh), TPB, 0, stream>>>(h_buf, pre, stats + bnidx*192,
                                            bn_g + bnidx*96, bn_b + bnidx*96, nullptr, 1, nh, inv_n);
  };

  // ---- GAT layer 0 (input dim 32, no residual) ----
  k_gemm_t   <<<gg, GTPB, 0, stream>>>(x, gat0_W, nullptr, big, N, 32, gat0_att, asrc, adst);
  k_gat_fused<<<wave_blocks, TPB, 0, stream>>>(asrc, adst, big, rowptr, idx_gat, gat0_b,
                                               pre, stats, N, EN);
  k_apply2   <<<g1(nh), TPB, 0, stream>>>(h_buf, pre, stats, bn_g, bn_b, nullptr, 0, nh, inv_n);

  // ---- GAT layers 1..3 ----
  for (int i = 0; i < 3; i++){
    int li = i + 1;
    int bnidx = 1 + i;
    k_gemm_t   <<<gg, GTPB, 0, stream>>>(h_buf, gat_W + (size_t)i*3*96*96, nullptr, big, N, 96,
                                         gat_att + i*3*192, asrc, adst);
    k_gat_fused<<<wave_blocks, TPB, 0, stream>>>(asrc, adst, big, rowptr, idx_gat,
                                                 gat_b + i*3*96, pre, stats + bnidx*192, N, EN);
    const float* inj = nullptr;
    if (li == 2 || li == 3){
      k_gemm_t<<<g1m, GTPB, 0, stream>>>(x, proj_W + (size_t)(li-2)*32*96, proj_b + (li-2)*96,
                                         aux, N, 32, nullptr, nullptr, nullptr);
      inj = aux;
    }
    k_apply2<<<g1(nh), TPB, 0, stream>>>(h_buf, pre, stats + bnidx*192,
                                         bn_g + bnidx*96, bn_b + bnidx*96, inj, 1, nh, inv_n);
    if (li == 1) run_hgt(0, 4);
  }
  run_hgt(1, 5);

  k_final_lin<<<g1(N), TPB, 0, stream>>>(h_buf, lin_W, lin_b, out, N);
}

// Round 7
// 1042.825 us; speedup vs baseline: 1.2737x; 1.2737x over previous
//
#include <hip/hip_runtime.h>
#include <math.h>

#define TPB 256

__device__ __forceinline__ float lrelu(float x){ return x > 0.f ? x : 0.2f*x; }

// ---------------- CSR build (graph constant across layers) ----------------
__global__ void k_init_cnt(int* __restrict__ cnt, int N){
  int t = blockIdx.x*TPB + threadIdx.x;
  if (t < 4*N) cnt[t] = (t < 3*N) ? 1 : 0;  // GAT counts start at 1 (self-loop)
}

__global__ void k_count(const int* __restrict__ ei, int* __restrict__ cnt, int N, int E){
  int t = blockIdx.x*TPB + threadIdx.x;
  if (t >= 3*E) return;
  int r = t / E, e = t - r*E;
  int dst = ei[(r*2+1)*E + e];
  atomicAdd(&cnt[r*N + dst], 1);
  atomicAdd(&cnt[3*N + dst], 1);
}

// scan + cursor init fused
__global__ void k_scan4(const int* __restrict__ cnt, int* __restrict__ rp,
                        int* __restrict__ cur, int N){
  __shared__ int sh[1024];
  __shared__ int carry;
  int a = blockIdx.x;
  const int* c = cnt + a*N;
  int* r = rp + a*(N+1);
  if (threadIdx.x == 0) carry = 0;
  __syncthreads();
  for (int base = 0; base < N; base += 1024){
    int idx = base + threadIdx.x;
    int v = (idx < N) ? c[idx] : 0;
    sh[threadIdx.x] = v;
    __syncthreads();
    for (int off = 1; off < 1024; off <<= 1){
      int t = (threadIdx.x >= off) ? sh[threadIdx.x - off] : 0;
      __syncthreads();
      sh[threadIdx.x] += t;
      __syncthreads();
    }
    if (idx < N){
      int ex = carry + sh[threadIdx.x] - v;   // exclusive
      r[idx] = ex;
      cur[a*N + idx] = ex;
    }
    __syncthreads();
    if (threadIdx.x == 0) carry += sh[1023];
    __syncthreads();
  }
  if (threadIdx.x == 0) r[N] = carry;
}

__global__ void k_scatter(const int* __restrict__ ei, int* __restrict__ cur,
                          int* __restrict__ idx_gat,
                          int* __restrict__ idx_hgt, int* __restrict__ idx_hgt_dst,
                          int N, int E){
  int t = blockIdx.x*TPB + threadIdx.x;
  int EN = E + N;
  if (t < 3*E){
    int r = t / E, e = t - r*E;
    int src = ei[(r*2)*E + e];
    int dst = ei[(r*2+1)*E + e];
    int pg = atomicAdd(&cur[r*N + dst], 1);
    idx_gat[r*EN + pg] = src;
    int ph = atomicAdd(&cur[3*N + dst], 1);
    idx_hgt[ph] = r*N + src;           // packed (rel,src)
    idx_hgt_dst[ph] = dst;
  } else if (t < 3*E + 3*N){
    int tt = t - 3*E;
    int r = tt / N, i = tt - r*N;
    int pg = atomicAdd(&cur[r*N + i], 1);
    idx_gat[r*EN + pg] = i;            // self loop
  }
}

// ---------------- LDS-tiled dense GEMM: C[mat] = A @ W[mat] (+ bias) ----------------
#define GTPB 192
__global__ __launch_bounds__(GTPB) void k_gemm_t(const float* __restrict__ A,
                        const float* __restrict__ W,
                        const float* __restrict__ bias, float* __restrict__ C,
                        int n, int K){
  __shared__ float Wl[96*96];
  int mat = blockIdx.y;
  const float4* Wm4 = reinterpret_cast<const float4*>(W + (size_t)mat*K*96);
  for (int idx = threadIdx.x; idx < K*24; idx += GTPB)
    reinterpret_cast<float4*>(Wl)[idx] = Wm4[idx];
  __syncthreads();

  int cg = threadIdx.x % 12;
  int rg = threadIdx.x / 12;     // 0..15
  int c0 = cg*8;
  int r0 = blockIdx.x*96 + rg*6;

  float acc[6][8];
  #pragma unroll
  for (int u = 0; u < 6; u++)
    #pragma unroll
    for (int c = 0; c < 8; c++) acc[u][c] = 0.f;

  for (int k = 0; k < K; k += 4){
    float4 a[6];
    #pragma unroll
    for (int u = 0; u < 6; u++){
      int r = r0 + u;
      a[u] = (r < n) ? *reinterpret_cast<const float4*>(A + (size_t)r*K + k)
                     : make_float4(0.f,0.f,0.f,0.f);
    }
    #pragma unroll
    for (int kk = 0; kk < 4; kk++){
      float4 w0 = *reinterpret_cast<const float4*>(Wl + (k+kk)*96 + c0);
      float4 w1 = *reinterpret_cast<const float4*>(Wl + (k+kk)*96 + c0 + 4);
      float wv0 = w0.x, wv1 = w0.y, wv2 = w0.z, wv3 = w0.w;
      float wv4 = w1.x, wv5 = w1.y, wv6 = w1.z, wv7 = w1.w;
      #pragma unroll
      for (int u = 0; u < 6; u++){
        float av = (kk==0) ? a[u].x : (kk==1) ? a[u].y : (kk==2) ? a[u].z : a[u].w;
        acc[u][0] += av*wv0; acc[u][1] += av*wv1; acc[u][2] += av*wv2; acc[u][3] += av*wv3;
        acc[u][4] += av*wv4; acc[u][5] += av*wv5; acc[u][6] += av*wv6; acc[u][7] += av*wv7;
      }
    }
  }

  float b[8];
  if (bias){
    const float* bp = bias + mat*96 + c0;
    #pragma unroll
    for (int c = 0; c < 8; c++) b[c] = bp[c];
  } else {
    #pragma unroll
    for (int c = 0; c < 8; c++) b[c] = 0.f;
  }
  #pragma unroll
  for (int u = 0; u < 6; u++){
    int r = r0 + u;
    if (r < n){
      float* Cr = C + (size_t)mat*n*96 + (size_t)r*96 + c0;
      float4 o0 = make_float4(acc[u][0]+b[0], acc[u][1]+b[1], acc[u][2]+b[2], acc[u][3]+b[3]);
      float4 o1 = make_float4(acc[u][4]+b[4], acc[u][5]+b[5], acc[u][6]+b[6], acc[u][7]+b[7]);
      reinterpret_cast<float4*>(Cr)[0] = o0;
      reinterpret_cast<float4*>(Cr)[1] = o1;
    }
  }
}

// ---------------- HGT effective-weight prep: fold a_rel/m_rel/p_rel into kqv weights ----
// Wbig[7][96][96]: mat0=q, mat1..3=K_r (scaled by 0.25*p_rel), mat4..6=V_r. bbig[7][96].
__global__ void k_prep(const float* __restrict__ kW, const float* __restrict__ kb,
                       const float* __restrict__ arel, const float* __restrict__ mrel,
                       const float* __restrict__ prel,
                       float* __restrict__ Wbig, float* __restrict__ bbig){
  int t = blockIdx.x*TPB + threadIdx.x;
  const int total = 7*96*96;
  if (t < total){
    int m = t / (96*96);
    int rem = t - m*(96*96);
    int c = rem / 96;
    int o = rem - c*96;
    float val;
    if (m == 0){
      val = kW[(size_t)96*96 + c*96 + o];            // q weights
    } else {
      int r = (m - 1) % 3;
      bool isV = m >= 4;
      const float* base = isV ? mrel : arel;         // [3][6][16][16]
      const float* wsrc = kW + (size_t)(isV ? 2 : 0)*96*96;
      int h = o >> 4, ff = o & 15;
      float s = 0.f;
      #pragma unroll
      for (int d = 0; d < 16; d++)
        s += wsrc[c*96 + h*16 + d] * base[(size_t)((r*6 + h)*16 + d)*16 + ff];
      if (!isV) s *= 0.25f * prel[r*6 + h];
      val = s;
    }
    Wbig[t] = val;
  } else if (t < total + 7*96){
    int tt = t - total;
    int m = tt / 96, o = tt - m*96;
    float val;
    if (m == 0){
      val = kb[96 + o];
    } else {
      int r = (m - 1) % 3;
      bool isV = m >= 4;
      const float* base = isV ? mrel : arel;
      const float* bsrc = kb + (isV ? 2 : 0)*96;
      int h = o >> 4, ff = o & 15;
      float s = 0.f;
      #pragma unroll
      for (int d = 0; d < 16; d++)
        s += bsrc[h*16 + d] * base[(size_t)((r*6 + h)*16 + d)*16 + ff];
      if (!isV) s *= 0.25f * prel[r*6 + h];
      val = s;
    }
    bbig[tt] = val;
  }
}

// ---------------- GAT attention dots: a_src/a_dst [3,N,2] ----------------
__global__ void k_attdots(const float* __restrict__ hp, const float* __restrict__ att,
                          float* __restrict__ asrc, float* __restrict__ adst, int n){
  int t = blockIdx.x*TPB + threadIdx.x;
  if (t >= 3*n) return;
  int r = t / n;                       // t == r*n+i
  const float* row = hp + (size_t)t*96;
  const float* ap  = att + r*192;      // [2,2,48] per relation
  #pragma unroll
  for (int h = 0; h < 2; h++){
    float s = 0.f, d = 0.f;
    #pragma unroll 8
    for (int dd = 0; dd < 48; dd++){
      float v = row[h*48 + dd];
      s += v * ap[h*48 + dd];
      d += v * ap[96 + h*48 + dd];
    }
    asrc[t*2 + h] = s;
    adst[t*2 + h] = d;
  }
}

// ---------------- GAT fused: wave per node; 3 relations; weights + gather + combine + bias ----
__global__ __launch_bounds__(TPB) void k_gat_fused(const float* __restrict__ asrc,
                        const float* __restrict__ adst, const float* __restrict__ hp,
                        const int* __restrict__ rowptr, const int* __restrict__ idxg,
                        const float* __restrict__ b3, float* __restrict__ pre,
                        int n, int EN){
  int wid = (blockIdx.x*TPB + threadIdx.x) >> 6;   // wave id = node
  if (wid >= n) return;
  int lane = threadIdx.x & 63;
  float comb_a = 0.f, comb_b = 0.f;
  #pragma unroll
  for (int r = 0; r < 3; r++){
    const int* rp = rowptr + r*(n+1);
    int s0 = rp[wid], s1 = rp[wid+1];
    const int* ix = idxg + (size_t)r*EN;
    const float2* as2 = reinterpret_cast<const float2*>(asrc) + (size_t)r*n;
    float2 ad = (reinterpret_cast<const float2*>(adst) + (size_t)r*n)[wid];
    const float* hpb = hp + (size_t)r*n*96;
    float acc_a = 0.f, acc_b = 0.f, ss0 = 0.f, ss1 = 0.f;
    for (int base = s0; base < s1; base += 64){
      int cnt = min(64, s1 - base);
      int src_l = 0; float w0_l = 0.f, w1_l = 0.f;
      if (lane < cnt){
        src_l = ix[base + lane];
        float2 av = as2[src_l];
        w0_l = __expf(fminf(lrelu(av.x + ad.x), 80.f));
        w1_l = __expf(fminf(lrelu(av.y + ad.y), 80.f));
      }
      for (int j = 0; j < cnt; j++){
        int   src = __shfl(src_l, j);
        float w0  = __shfl(w0_l, j);
        float w1  = __shfl(w1_l, j);
        const float* row = hpb + (size_t)src*96;
        float va = row[lane];
        float vb = (lane < 32) ? row[64 + lane] : 0.f;
        float wa = (lane < 48) ? w0 : w1;
        acc_a += wa*va;
        acc_b += w1*vb;
        ss0 += w0; ss1 += w1;
      }
    }
    comb_a += acc_a / ((lane < 48) ? ss0 : ss1);   // self-loop => non-empty
    comb_b += acc_b / ss1;
  }
  comb_a += b3[lane] + b3[96 + lane] + b3[192 + lane];
  float* pr = pre + (size_t)wid*96;
  pr[lane] = comb_a;
  if (lane < 32){
    comb_b += b3[64 + lane] + b3[160 + lane] + b3[256 + lane];
    pr[64 + lane] = comb_b;
  }
}

// ---------------- BN stats over pre: grid-stride sum/sumsq ----------------
__global__ void k_stats(const float* __restrict__ pre, float* __restrict__ stats, int total){
  __shared__ float s1[96], s2[96];
  if (threadIdx.x < 96){ s1[threadIdx.x] = 0.f; s2[threadIdx.x] = 0.f; }
  __syncthreads();
  int idx0 = blockIdx.x*TPB*8 + threadIdx.x;
  for (int it = 0; it < 8; it++){
    int idx = idx0 + it*TPB;
    if (idx < total){
      int c = idx % 96;
      float v = pre[idx];
      atomicAdd(&s1[c], v);
      atomicAdd(&s2[c], v*v);
    }
  }
  __syncthreads();
  if (threadIdx.x < 96){
    atomicAdd(&stats[threadIdx.x], s1[threadIdx.x]);
    atomicAdd(&stats[96 + threadIdx.x], s2[threadIdx.x]);
  }
}

// ---------------- HGT skip-mix in place + BN stats ----------------
__global__ void k_mix_stats(float* __restrict__ pre, const float* __restrict__ h,
                            const float* __restrict__ skip, float* __restrict__ stats, int total){
  __shared__ float s1[96], s2[96];
  if (threadIdx.x < 96){ s1[threadIdx.x] = 0.f; s2[threadIdx.x] = 0.f; }
  __syncthreads();
  float sk = 1.f / (1.f + expf(-skip[0]));
  int idx0 = blockIdx.x*TPB*8 + threadIdx.x;
  for (int it = 0; it < 8; it++){
    int idx = idx0 + it*TPB;
    if (idx < total){
      int c = idx % 96;
      float v = sk*pre[idx] + (1.f - sk)*h[idx];
      pre[idx] = v;
      atomicAdd(&s1[c], v);
      atomicAdd(&s2[c], v*v);
    }
  }
  __syncthreads();
  if (threadIdx.x < 96){
    atomicAdd(&stats[threadIdx.x], s1[threadIdx.x]);
    atomicAdd(&stats[96 + threadIdx.x], s2[threadIdx.x]);
  }
}

// ---------------- apply with inline BN finalize: h = lrelu(res*h + bn(pre) + inj) ----------------
__global__ void k_apply2(float* __restrict__ h, const float* __restrict__ pre,
                         const float* __restrict__ stats, const float* __restrict__ gamma,
                         const float* __restrict__ beta, const float* __restrict__ inj,
                         int res, int total, float inv_n){
  int idx = blockIdx.x*TPB + threadIdx.x;
  if (idx >= total) return;
  int c = idx % 96;
  float mean = stats[c] * inv_n;
  float var  = stats[96 + c] * inv_n - mean*mean;
  float sc   = gamma[c] * rsqrtf(var + 1e-5f);
  float sh   = beta[c] - mean*sc;
  float v = sc*pre[idx] + sh;
  if (inj) v += inj[idx];
  if (res) v += h[idx];
  h[idx] = lrelu(v);
}

// ---------------- HGT phase A: per-(slot,head) edge weights (scale pre-folded) ----------------
__global__ void k_hgt_w(const float* __restrict__ q, const float* __restrict__ Kb,
                        const int* __restrict__ idxh, const int* __restrict__ idxh_dst,
                        float* __restrict__ wbuf, int n, int totE){
  int t = blockIdx.x*TPB + threadIdx.x;
  if (t >= totE*6) return;
  int slot = t / 6, h = t - slot*6;
  int packed = idxh[slot];
  int dst = idxh_dst[slot];
  const float4* kp = reinterpret_cast<const float4*>(Kb + (size_t)packed*96 + h*16);
  const float4* qp = reinterpret_cast<const float4*>(q + (size_t)dst*96 + h*16);
  float dot = 0.f;
  #pragma unroll
  for (int w = 0; w < 4; w++){
    float4 kv = kp[w], qv = qp[w];
    dot += kv.x*qv.x + kv.y*qv.y + kv.z*qv.z + kv.w*qv.w;
  }
  wbuf[t] = __expf(fminf(dot, 80.f));
}

// ---------------- HGT fused gather: wave per node; shfl-staged; + GELU ----------------
__global__ __launch_bounds__(TPB) void k_hgt_fused(const float* __restrict__ wbuf,
                        const float* __restrict__ Vb, const int* __restrict__ rp4,
                        const int* __restrict__ idxh, float* __restrict__ gbuf, int n){
  int wid = (blockIdx.x*TPB + threadIdx.x) >> 6;
  if (wid >= n) return;
  int lane = threadIdx.x & 63;
  const int* rp = rp4 + 3*(n+1);
  int s0 = rp[wid], s1 = rp[wid+1];
  int ha = lane >> 4;                         // head for col=lane (0..3)
  float acc_a = 0.f, acc_b = 0.f, ss_a = 0.f, ss_b = 0.f;
  for (int base = s0; base < s1; base += 64){
    int cnt = min(64, s1 - base);
    int pk = 0; float w0=0.f,w1=0.f,w2=0.f,w3=0.f,w4=0.f,w5=0.f;
    if (lane < cnt){
      int slot = base + lane;
      pk = idxh[slot];
      const float2* wp = reinterpret_cast<const float2*>(wbuf + (size_t)slot*6);
      float2 p0 = wp[0], p1 = wp[1], p2 = wp[2];
      w0=p0.x; w1=p0.y; w2=p1.x; w3=p1.y; w4=p2.x; w5=p2.y;
    }
    for (int j = 0; j < cnt; j++){
      int packed = __shfl(pk, j);
      float b0=__shfl(w0,j), b1=__shfl(w1,j), b2=__shfl(w2,j),
            b3v=__shfl(w3,j), b4=__shfl(w4,j), b5=__shfl(w5,j);
      const float* row = Vb + (size_t)packed*96;
      float va = row[lane];
      float vb = (lane < 32) ? row[64 + lane] : 0.f;
      float wa = (ha==0) ? b0 : ((ha==1) ? b1 : ((ha==2) ? b2 : b3v));
      float wb = ((lane >> 4) == 0) ? b4 : b5;   // head 4/5 for cols 64..95
      acc_a += wa*va; ss_a += wa;
      acc_b += wb*vb; ss_b += wb;
    }
  }
  float xa = (s1 > s0) ? acc_a/ss_a : 0.f;
  float* gb = gbuf + (size_t)wid*96;
  gb[lane] = 0.5f*xa*(1.f + erff(xa*0.70710678118654752f));
  if (lane < 32){
    float xb = (s1 > s0) ? acc_b/ss_b : 0.f;
    gb[64 + lane] = 0.5f*xb*(1.f + erff(xb*0.70710678118654752f));
  }
}

// ---------------- final linear ----------------
__global__ void k_final_lin(const float* __restrict__ h, const float* __restrict__ w,
                            const float* __restrict__ b, float* __restrict__ out, int N){
  int i = blockIdx.x*TPB + threadIdx.x;
  if (i >= N) return;
  const float4* hr = reinterpret_cast<const float4*>(h + (size_t)i*96);
  const float4* wr = reinterpret_cast<const float4*>(w);
  float acc = 0.f;
  #pragma unroll
  for (int c = 0; c < 24; c++){
    float4 a = hr[c], q = wr[c];
    acc += a.x*q.x + a.y*q.y + a.z*q.z + a.w*q.w;
  }
  out[i] = acc + b[0];
}

// =====================================================================
extern "C" void kernel_launch(void* const* d_in, const int* in_sizes, int n_in,
                              void* d_out, int out_size, void* d_ws, size_t ws_size,
                              hipStream_t stream){
  const float* x        = (const float*)d_in[0];
  const int*   ei       = (const int*)  d_in[1];
  const float* gat0_W   = (const float*)d_in[2];
  const float* gat0_att = (const float*)d_in[3];
  const float* gat0_b   = (const float*)d_in[4];
  const float* gat_W    = (const float*)d_in[5];
  const float* gat_att  = (const float*)d_in[6];
  const float* gat_b    = (const float*)d_in[7];
  const float* bn_g     = (const float*)d_in[8];
  const float* bn_b     = (const float*)d_in[9];
  const float* kqv_W    = (const float*)d_in[10];
  const float* kqv_b    = (const float*)d_in[11];
  const float* a_rel    = (const float*)d_in[12];
  const float* m_rel    = (const float*)d_in[13];
  const float* p_rel    = (const float*)d_in[14];
  const float* hout_W   = (const float*)d_in[15];
  const float* hout_b   = (const float*)d_in[16];
  const float* skip     = (const float*)d_in[17];
  const float* proj_W   = (const float*)d_in[18];
  const float* proj_b   = (const float*)d_in[19];
  const float* lin_W    = (const float*)d_in[20];
  const float* lin_b    = (const float*)d_in[21];
  float* out = (float*)d_out;

  const int N = in_sizes[0] / 32;
  const int E = in_sizes[1] / 6;
  const int EN = E + N;
  const size_t NH = (size_t)N * 96;
  const int nh = (int)NH;
  const float inv_n = 1.f / (float)N;

  // ---- workspace layout (floats, then ints) ----
  float* f = (float*)d_ws;
  float* h_buf = f;  f += NH;
  float* pre   = f;  f += NH;        // aliased as wbuf (HGT phase A->B window)
  float* big   = f;  f += 9*NH;      // GAT: hp[3]; HGT: qKV[7] (q,K0..2,V0..2)
  float* aux   = f;  f += NH;        // injection | gelu(agg)
  float* asrc  = f;  f += (size_t)3*N*2;
  float* adst  = f;  f += (size_t)3*N*2;
  float* stats = f;  f += 6*192;     // 6 BN slots of (sum[96], sumsq[96])
  float* Wbig  = f;  f += 7*96*96;
  float* bbig  = f;  f += 7*96;
  int* ip = (int*)f;
  int* cnt     = ip;  ip += 4*N;
  int* rowptr  = ip;  ip += 4*(N+1);
  int* cursor  = ip;  ip += 4*N;
  int* idx_gat     = ip;  ip += 3*EN;
  int* idx_hgt     = ip;  ip += 3*E;
  int* idx_hgt_dst = ip;  ip += 3*E;
  float* wbuf = pre;                 // 3E*6 = 1.8M floats <= NH

  auto g1 = [](int n){ return dim3((n + TPB - 1)/TPB); };
  const int gx = (N + 95)/96;                 // GEMM row-tiles
  const dim3 gg(gx, 3);                       // 3-matrix GEMM grid
  const dim3 gg7(gx, 7);                      // 7-matrix HGT qKV grid
  const dim3 g1m(gx, 1);                      // 1-matrix GEMM grid
  const int cs_blocks = (nh + TPB*8 - 1)/(TPB*8);
  const int wave_blocks = (N + 3)/4;          // 4 waves (nodes) per 256-block

  // ---- CSR build + stats zero ----
  hipMemsetAsync(stats, 0, 6*192*sizeof(float), stream);
  k_init_cnt<<<g1(4*N),     TPB, 0, stream>>>(cnt, N);
  k_count   <<<g1(3*E),     TPB, 0, stream>>>(ei, cnt, N, E);
  k_scan4   <<<4,          1024, 0, stream>>>(cnt, rowptr, cursor, N);
  k_scatter <<<g1(3*E+3*N), TPB, 0, stream>>>(ei, cursor, idx_gat, idx_hgt, idx_hgt_dst, N, E);

  auto run_hgt = [&](int idx, int bnidx){
    k_prep     <<<g1(7*96*96 + 7*96), TPB, 0, stream>>>(
                   kqv_W + (size_t)idx*3*96*96, kqv_b + idx*3*96,
                   a_rel + (size_t)idx*3*6*256, m_rel + (size_t)idx*3*6*256,
                   p_rel + idx*18, Wbig, bbig);
    k_gemm_t   <<<gg7, GTPB, 0, stream>>>(h_buf, Wbig, bbig, big, N, 96);
    k_hgt_w    <<<g1(3*E*6), TPB, 0, stream>>>(big, big + NH, idx_hgt, idx_hgt_dst, wbuf, N, 3*E);
    k_hgt_fused<<<wave_blocks, TPB, 0, stream>>>(wbuf, big + 4*NH, rowptr, idx_hgt, aux, N);
    k_gemm_t   <<<g1m, GTPB, 0, stream>>>(aux, hout_W + (size_t)idx*96*96, hout_b + idx*96, pre, N, 96);
    k_mix_stats<<<cs_blocks, TPB, 0, stream>>>(pre, h_buf, skip + idx, stats + bnidx*192, nh);
    k_apply2   <<<g1(nh), TPB, 0, stream>>>(h_buf, pre, stats + bnidx*192,
                                            bn_g + bnidx*96, bn_b + bnidx*96, nullptr, 1, nh, inv_n);
  };

  // ---- GAT layer 0 (input dim 32, no residual) ----
  k_gemm_t   <<<gg, GTPB, 0, stream>>>(x, gat0_W, nullptr, big, N, 32);
  k_attdots  <<<g1(3*N), TPB, 0, stream>>>(big, gat0_att, asrc, adst, N);
  k_gat_fused<<<wave_blocks, TPB, 0, stream>>>(asrc, adst, big, rowptr, idx_gat, gat0_b, pre, N, EN);
  k_stats    <<<cs_blocks, TPB, 0, stream>>>(pre, stats, nh);
  k_apply2   <<<g1(nh), TPB, 0, stream>>>(h_buf, pre, stats, bn_g, bn_b, nullptr, 0, nh, inv_n);

  // ---- GAT layers 1..3 ----
  for (int i = 0; i < 3; i++){
    int li = i + 1;
    int bnidx = 1 + i;
    k_gemm_t   <<<gg, GTPB, 0, stream>>>(h_buf, gat_W + (size_t)i*3*96*96, nullptr, big, N, 96);
    k_attdots  <<<g1(3*N), TPB, 0, stream>>>(big, gat_att + i*3*192, asrc, adst, N);
    k_gat_fused<<<wave_blocks, TPB, 0, stream>>>(asrc, adst, big, rowptr, idx_gat,
                                                 gat_b + i*3*96, pre, N, EN);
    k_stats    <<<cs_blocks, TPB, 0, stream>>>(pre, stats + bnidx*192, nh);
    const float* inj = nullptr;
    if (li == 2 || li == 3){
      k_gemm_t<<<g1m, GTPB, 0, stream>>>(x, proj_W + (size_t)(li-2)*32*96, proj_b + (li-2)*96, aux, N, 32);
      inj = aux;
    }
    k_apply2<<<g1(nh), TPB, 0, stream>>>(h_buf, pre, stats + bnidx*192,
                                         bn_g + bnidx*96, bn_b + bnidx*96, inj, 1, nh, inv_n);
    if (li == 1) run_hgt(0, 4);
  }
  run_hgt(1, 5);

  k_final_lin<<<g1(N), TPB, 0, stream>>>(h_buf, lin_W, lin_b, out, N);
}

// Round 8
// 938.020 us; speedup vs baseline: 1.4161x; 1.1117x over previous
//
#include <hip/hip_runtime.h>
#include <math.h>

#define TPB 256

__device__ __forceinline__ float lrelu(float x){ return x > 0.f ? x : 0.2f*x; }

// ---------------- CSR build (graph constant across layers) ----------------
__global__ void k_init_cnt(int* __restrict__ cnt, int N){
  int t = blockIdx.x*TPB + threadIdx.x;
  if (t < 4*N) cnt[t] = (t < 3*N) ? 1 : 0;  // GAT counts start at 1 (self-loop)
}

__global__ void k_count(const int* __restrict__ ei, int* __restrict__ cnt, int N, int E){
  int t = blockIdx.x*TPB + threadIdx.x;
  if (t >= 3*E) return;
  int r = t / E, e = t - r*E;
  int dst = ei[(r*2+1)*E + e];
  atomicAdd(&cnt[r*N + dst], 1);
  atomicAdd(&cnt[3*N + dst], 1);
}

// scan + cursor init fused
__global__ void k_scan4(const int* __restrict__ cnt, int* __restrict__ rp,
                        int* __restrict__ cur, int N){
  __shared__ int sh[1024];
  __shared__ int carry;
  int a = blockIdx.x;
  const int* c = cnt + a*N;
  int* r = rp + a*(N+1);
  if (threadIdx.x == 0) carry = 0;
  __syncthreads();
  for (int base = 0; base < N; base += 1024){
    int idx = base + threadIdx.x;
    int v = (idx < N) ? c[idx] : 0;
    sh[threadIdx.x] = v;
    __syncthreads();
    for (int off = 1; off < 1024; off <<= 1){
      int t = (threadIdx.x >= off) ? sh[threadIdx.x - off] : 0;
      __syncthreads();
      sh[threadIdx.x] += t;
      __syncthreads();
    }
    if (idx < N){
      int ex = carry + sh[threadIdx.x] - v;   // exclusive
      r[idx] = ex;
      cur[a*N + idx] = ex;
    }
    __syncthreads();
    if (threadIdx.x == 0) carry += sh[1023];
    __syncthreads();
  }
  if (threadIdx.x == 0) r[N] = carry;
}

__global__ void k_scatter(const int* __restrict__ ei, int* __restrict__ cur,
                          int* __restrict__ idx_gat,
                          int* __restrict__ idx_hgt, int* __restrict__ idx_hgt_dst,
                          int N, int E){
  int t = blockIdx.x*TPB + threadIdx.x;
  int EN = E + N;
  if (t < 3*E){
    int r = t / E, e = t - r*E;
    int src = ei[(r*2)*E + e];
    int dst = ei[(r*2+1)*E + e];
    int pg = atomicAdd(&cur[r*N + dst], 1);
    idx_gat[r*EN + pg] = src;
    int ph = atomicAdd(&cur[3*N + dst], 1);
    idx_hgt[ph] = r*N + src;           // packed (rel,src)
    idx_hgt_dst[ph] = dst;
  } else if (t < 3*E + 3*N){
    int tt = t - 3*E;
    int r = tt / N, i = tt - r*N;
    int pg = atomicAdd(&cur[r*N + i], 1);
    idx_gat[r*EN + pg] = i;            // self loop
  }
}

// ---------------- LDS-tiled dense GEMM: C[mat] = A @ W[mat] (+ bias) ----------------
// 384 threads/block -> 96x96 tile, 3 rows x 8 cols per thread.
// LDS 36KB -> 4 blocks/CU -> 24 waves/CU (vs 12 at 192 threads): latency hiding.
#define GTPB 384
__global__ __launch_bounds__(GTPB) void k_gemm_t(const float* __restrict__ A,
                        const float* __restrict__ W,
                        const float* __restrict__ bias, float* __restrict__ C,
                        int n, int K){
  __shared__ float Wl[96*96];
  int mat = blockIdx.y;
  const float4* Wm4 = reinterpret_cast<const float4*>(W + (size_t)mat*K*96);
  for (int idx = threadIdx.x; idx < K*24; idx += GTPB)
    reinterpret_cast<float4*>(Wl)[idx] = Wm4[idx];
  __syncthreads();

  int cg = threadIdx.x % 12;
  int rg = threadIdx.x / 12;     // 0..31
  int c0 = cg*8;
  int r0 = blockIdx.x*96 + rg*3;

  float acc[3][8];
  #pragma unroll
  for (int u = 0; u < 3; u++)
    #pragma unroll
    for (int c = 0; c < 8; c++) acc[u][c] = 0.f;

  for (int k = 0; k < K; k += 4){
    float4 a[3];
    #pragma unroll
    for (int u = 0; u < 3; u++){
      int r = r0 + u;
      a[u] = (r < n) ? *reinterpret_cast<const float4*>(A + (size_t)r*K + k)
                     : make_float4(0.f,0.f,0.f,0.f);
    }
    #pragma unroll
    for (int kk = 0; kk < 4; kk++){
      float4 w0 = *reinterpret_cast<const float4*>(Wl + (k+kk)*96 + c0);
      float4 w1 = *reinterpret_cast<const float4*>(Wl + (k+kk)*96 + c0 + 4);
      float wv0 = w0.x, wv1 = w0.y, wv2 = w0.z, wv3 = w0.w;
      float wv4 = w1.x, wv5 = w1.y, wv6 = w1.z, wv7 = w1.w;
      #pragma unroll
      for (int u = 0; u < 3; u++){
        float av = (kk==0) ? a[u].x : (kk==1) ? a[u].y : (kk==2) ? a[u].z : a[u].w;
        acc[u][0] += av*wv0; acc[u][1] += av*wv1; acc[u][2] += av*wv2; acc[u][3] += av*wv3;
        acc[u][4] += av*wv4; acc[u][5] += av*wv5; acc[u][6] += av*wv6; acc[u][7] += av*wv7;
      }
    }
  }

  float b[8];
  if (bias){
    const float* bp = bias + mat*96 + c0;
    #pragma unroll
    for (int c = 0; c < 8; c++) b[c] = bp[c];
  } else {
    #pragma unroll
    for (int c = 0; c < 8; c++) b[c] = 0.f;
  }
  #pragma unroll
  for (int u = 0; u < 3; u++){
    int r = r0 + u;
    if (r < n){
      float* Cr = C + (size_t)mat*n*96 + (size_t)r*96 + c0;
      float4 o0 = make_float4(acc[u][0]+b[0], acc[u][1]+b[1], acc[u][2]+b[2], acc[u][3]+b[3]);
      float4 o1 = make_float4(acc[u][4]+b[4], acc[u][5]+b[5], acc[u][6]+b[6], acc[u][7]+b[7]);
      reinterpret_cast<float4*>(Cr)[0] = o0;
      reinterpret_cast<float4*>(Cr)[1] = o1;
    }
  }
}

// ---------------- HGT effective-weight prep: fold a_rel/m_rel/p_rel into kqv weights ----
// Wbig[7][96][96]: mat0=q, mat1..3=K_r (scaled by 0.25*p_rel), mat4..6=V_r. bbig[7][96].
__global__ void k_prep(const float* __restrict__ kW, const float* __restrict__ kb,
                       const float* __restrict__ arel, const float* __restrict__ mrel,
                       const float* __restrict__ prel,
                       float* __restrict__ Wbig, float* __restrict__ bbig){
  int t = blockIdx.x*TPB + threadIdx.x;
  const int total = 7*96*96;
  if (t < total){
    int m = t / (96*96);
    int rem = t - m*(96*96);
    int c = rem / 96;
    int o = rem - c*96;
    float val;
    if (m == 0){
      val = kW[(size_t)96*96 + c*96 + o];            // q weights
    } else {
      int r = (m - 1) % 3;
      bool isV = m >= 4;
      const float* base = isV ? mrel : arel;         // [3][6][16][16]
      const float* wsrc = kW + (size_t)(isV ? 2 : 0)*96*96;
      int h = o >> 4, ff = o & 15;
      float s = 0.f;
      #pragma unroll
      for (int d = 0; d < 16; d++)
        s += wsrc[c*96 + h*16 + d] * base[(size_t)((r*6 + h)*16 + d)*16 + ff];
      if (!isV) s *= 0.25f * prel[r*6 + h];
      val = s;
    }
    Wbig[t] = val;
  } else if (t < total + 7*96){
    int tt = t - total;
    int m = tt / 96, o = tt - m*96;
    float val;
    if (m == 0){
      val = kb[96 + o];
    } else {
      int r = (m - 1) % 3;
      bool isV = m >= 4;
      const float* base = isV ? mrel : arel;
      const float* bsrc = kb + (isV ? 2 : 0)*96;
      int h = o >> 4, ff = o & 15;
      float s = 0.f;
      #pragma unroll
      for (int d = 0; d < 16; d++)
        s += bsrc[h*16 + d] * base[(size_t)((r*6 + h)*16 + d)*16 + ff];
      if (!isV) s *= 0.25f * prel[r*6 + h];
      val = s;
    }
    bbig[tt] = val;
  }
}

// ---------------- GAT attention dots: a_src/a_dst [3,N,2] ----------------
__global__ void k_attdots(const float* __restrict__ hp, const float* __restrict__ att,
                          float* __restrict__ asrc, float* __restrict__ adst, int n){
  int t = blockIdx.x*TPB + threadIdx.x;
  if (t >= 3*n) return;
  int r = t / n;                       // t == r*n+i
  const float* row = hp + (size_t)t*96;
  const float* ap  = att + r*192;      // [2,2,48] per relation
  #pragma unroll
  for (int h = 0; h < 2; h++){
    float s = 0.f, d = 0.f;
    #pragma unroll 8
    for (int dd = 0; dd < 48; dd++){
      float v = row[h*48 + dd];
      s += v * ap[h*48 + dd];
      d += v * ap[96 + h*48 + dd];
    }
    asrc[t*2 + h] = s;
    adst[t*2 + h] = d;
  }
}

// ---------------- GAT fused: wave per node; 3 relations; weights + gather + combine + bias ----
__global__ __launch_bounds__(TPB) void k_gat_fused(const float* __restrict__ asrc,
                        const float* __restrict__ adst, const float* __restrict__ hp,
                        const int* __restrict__ rowptr, const int* __restrict__ idxg,
                        const float* __restrict__ b3, float* __restrict__ pre,
                        int n, int EN){
  int wid = (blockIdx.x*TPB + threadIdx.x) >> 6;   // wave id = node
  if (wid >= n) return;
  int lane = threadIdx.x & 63;
  float comb_a = 0.f, comb_b = 0.f;
  #pragma unroll
  for (int r = 0; r < 3; r++){
    const int* rp = rowptr + r*(n+1);
    int s0 = rp[wid], s1 = rp[wid+1];
    const int* ix = idxg + (size_t)r*EN;
    const float2* as2 = reinterpret_cast<const float2*>(asrc) + (size_t)r*n;
    float2 ad = (reinterpret_cast<const float2*>(adst) + (size_t)r*n)[wid];
    const float* hpb = hp + (size_t)r*n*96;
    float acc_a = 0.f, acc_b = 0.f, ss0 = 0.f, ss1 = 0.f;
    for (int base = s0; base < s1; base += 64){
      int cnt = min(64, s1 - base);
      int src_l = 0; float w0_l = 0.f, w1_l = 0.f;
      if (lane < cnt){
        src_l = ix[base + lane];
        float2 av = as2[src_l];
        w0_l = __expf(fminf(lrelu(av.x + ad.x), 80.f));
        w1_l = __expf(fminf(lrelu(av.y + ad.y), 80.f));
      }
      for (int j = 0; j < cnt; j++){
        int   src = __shfl(src_l, j);
        float w0  = __shfl(w0_l, j);
        float w1  = __shfl(w1_l, j);
        const float* row = hpb + (size_t)src*96;
        float va = row[lane];
        float vb = (lane < 32) ? row[64 + lane] : 0.f;
        float wa = (lane < 48) ? w0 : w1;
        acc_a += wa*va;
        acc_b += w1*vb;
        ss0 += w0; ss1 += w1;
      }
    }
    comb_a += acc_a / ((lane < 48) ? ss0 : ss1);   // self-loop => non-empty
    comb_b += acc_b / ss1;
  }
  comb_a += b3[lane] + b3[96 + lane] + b3[192 + lane];
  float* pr = pre + (size_t)wid*96;
  pr[lane] = comb_a;
  if (lane < 32){
    comb_b += b3[64 + lane] + b3[160 + lane] + b3[256 + lane];
    pr[64 + lane] = comb_b;
  }
}

// ---------------- BN stats over pre: grid-stride sum/sumsq ----------------
__global__ void k_stats(const float* __restrict__ pre, float* __restrict__ stats, int total){
  __shared__ float s1[96], s2[96];
  if (threadIdx.x < 96){ s1[threadIdx.x] = 0.f; s2[threadIdx.x] = 0.f; }
  __syncthreads();
  int idx0 = blockIdx.x*TPB*8 + threadIdx.x;
  for (int it = 0; it < 8; it++){
    int idx = idx0 + it*TPB;
    if (idx < total){
      int c = idx % 96;
      float v = pre[idx];
      atomicAdd(&s1[c], v);
      atomicAdd(&s2[c], v*v);
    }
  }
  __syncthreads();
  if (threadIdx.x < 96){
    atomicAdd(&stats[threadIdx.x], s1[threadIdx.x]);
    atomicAdd(&stats[96 + threadIdx.x], s2[threadIdx.x]);
  }
}

// ---------------- HGT skip-mix in place + BN stats ----------------
__global__ void k_mix_stats(float* __restrict__ pre, const float* __restrict__ h,
                            const float* __restrict__ skip, float* __restrict__ stats, int total){
  __shared__ float s1[96], s2[96];
  if (threadIdx.x < 96){ s1[threadIdx.x] = 0.f; s2[threadIdx.x] = 0.f; }
  __syncthreads();
  float sk = 1.f / (1.f + expf(-skip[0]));
  int idx0 = blockIdx.x*TPB*8 + threadIdx.x;
  for (int it = 0; it < 8; it++){
    int idx = idx0 + it*TPB;
    if (idx < total){
      int c = idx % 96;
      float v = sk*pre[idx] + (1.f - sk)*h[idx];
      pre[idx] = v;
      atomicAdd(&s1[c], v);
      atomicAdd(&s2[c], v*v);
    }
  }
  __syncthreads();
  if (threadIdx.x < 96){
    atomicAdd(&stats[threadIdx.x], s1[threadIdx.x]);
    atomicAdd(&stats[96 + threadIdx.x], s2[threadIdx.x]);
  }
}

// ---------------- apply with inline BN finalize: h = lrelu(res*h + bn(pre) + inj) ----------------
__global__ void k_apply2(float* __restrict__ h, const float* __restrict__ pre,
                         const float* __restrict__ stats, const float* __restrict__ gamma,
                         const float* __restrict__ beta, const float* __restrict__ inj,
                         int res, int total, float inv_n){
  int idx = blockIdx.x*TPB + threadIdx.x;
  if (idx >= total) return;
  int c = idx % 96;
  float mean = stats[c] * inv_n;
  float var  = stats[96 + c] * inv_n - mean*mean;
  float sc   = gamma[c] * rsqrtf(var + 1e-5f);
  float sh   = beta[c] - mean*sc;
  float v = sc*pre[idx] + sh;
  if (inj) v += inj[idx];
  if (res) v += h[idx];
  h[idx] = lrelu(v);
}

// ---------------- HGT phase A: per-(slot,head) edge weights (scale pre-folded) ----------------
__global__ void k_hgt_w(const float* __restrict__ q, const float* __restrict__ Kb,
                        const int* __restrict__ idxh, const int* __restrict__ idxh_dst,
                        float* __restrict__ wbuf, int n, int totE){
  int t = blockIdx.x*TPB + threadIdx.x;
  if (t >= totE*6) return;
  int slot = t / 6, h = t - slot*6;
  int packed = idxh[slot];
  int dst = idxh_dst[slot];
  const float4* kp = reinterpret_cast<const float4*>(Kb + (size_t)packed*96 + h*16);
  const float4* qp = reinterpret_cast<const float4*>(q + (size_t)dst*96 + h*16);
  float dot = 0.f;
  #pragma unroll
  for (int w = 0; w < 4; w++){
    float4 kv = kp[w], qv = qp[w];
    dot += kv.x*qv.x + kv.y*qv.y + kv.z*qv.z + kv.w*qv.w;
  }
  wbuf[t] = __expf(fminf(dot, 80.f));
}

// ---------------- HGT fused gather: wave per node; shfl-staged; + GELU ----------------
__global__ __launch_bounds__(TPB) void k_hgt_fused(const float* __restrict__ wbuf,
                        const float* __restrict__ Vb, const int* __restrict__ rp4,
                        const int* __restrict__ idxh, float* __restrict__ gbuf, int n){
  int wid = (blockIdx.x*TPB + threadIdx.x) >> 6;
  if (wid >= n) return;
  int lane = threadIdx.x & 63;
  const int* rp = rp4 + 3*(n+1);
  int s0 = rp[wid], s1 = rp[wid+1];
  int ha = lane >> 4;                         // head for col=lane (0..3)
  float acc_a = 0.f, acc_b = 0.f, ss_a = 0.f, ss_b = 0.f;
  for (int base = s0; base < s1; base += 64){
    int cnt = min(64, s1 - base);
    int pk = 0; float w0=0.f,w1=0.f,w2=0.f,w3=0.f,w4=0.f,w5=0.f;
    if (lane < cnt){
      int slot = base + lane;
      pk = idxh[slot];
      const float2* wp = reinterpret_cast<const float2*>(wbuf + (size_t)slot*6);
      float2 p0 = wp[0], p1 = wp[1], p2 = wp[2];
      w0=p0.x; w1=p0.y; w2=p1.x; w3=p1.y; w4=p2.x; w5=p2.y;
    }
    for (int j = 0; j < cnt; j++){
      int packed = __shfl(pk, j);
      float b0=__shfl(w0,j), b1=__shfl(w1,j), b2=__shfl(w2,j),
            b3v=__shfl(w3,j), b4=__shfl(w4,j), b5=__shfl(w5,j);
      const float* row = Vb + (size_t)packed*96;
      float va = row[lane];
      float vb = (lane < 32) ? row[64 + lane] : 0.f;
      float wa = (ha==0) ? b0 : ((ha==1) ? b1 : ((ha==2) ? b2 : b3v));
      float wb = ((lane >> 4) == 0) ? b4 : b5;   // head 4/5 for cols 64..95
      acc_a += wa*va; ss_a += wa;
      acc_b += wb*vb; ss_b += wb;
    }
  }
  float xa = (s1 > s0) ? acc_a/ss_a : 0.f;
  float* gb = gbuf + (size_t)wid*96;
  gb[lane] = 0.5f*xa*(1.f + erff(xa*0.70710678118654752f));
  if (lane < 32){
    float xb = (s1 > s0) ? acc_b/ss_b : 0.f;
    gb[64 + lane] = 0.5f*xb*(1.f + erff(xb*0.70710678118654752f));
  }
}

// ---------------- final linear ----------------
__global__ void k_final_lin(const float* __restrict__ h, const float* __restrict__ w,
                            const float* __restrict__ b, float* __restrict__ out, int N){
  int i = blockIdx.x*TPB + threadIdx.x;
  if (i >= N) return;
  const float4* hr = reinterpret_cast<const float4*>(h + (size_t)i*96);
  const float4* wr = reinterpret_cast<const float4*>(w);
  float acc = 0.f;
  #pragma unroll
  for (int c = 0; c < 24; c++){
    float4 a = hr[c], q = wr[c];
    acc += a.x*q.x + a.y*q.y + a.z*q.z + a.w*q.w;
  }
  out[i] = acc + b[0];
}

// =====================================================================
extern "C" void kernel_launch(void* const* d_in, const int* in_sizes, int n_in,
                              void* d_out, int out_size, void* d_ws, size_t ws_size,
                              hipStream_t stream){
  const float* x        = (const float*)d_in[0];
  const int*   ei       = (const int*)  d_in[1];
  const float* gat0_W   = (const float*)d_in[2];
  const float* gat0_att = (const float*)d_in[3];
  const float* gat0_b   = (const float*)d_in[4];
  const float* gat_W    = (const float*)d_in[5];
  const float* gat_att  = (const float*)d_in[6];
  const float* gat_b    = (const float*)d_in[7];
  const float* bn_g     = (const float*)d_in[8];
  const float* bn_b     = (const float*)d_in[9];
  const float* kqv_W    = (const float*)d_in[10];
  const float* kqv_b    = (const float*)d_in[11];
  const float* a_rel    = (const float*)d_in[12];
  const float* m_rel    = (const float*)d_in[13];
  const float* p_rel    = (const float*)d_in[14];
  const float* hout_W   = (const float*)d_in[15];
  const float* hout_b   = (const float*)d_in[16];
  const float* skip     = (const float*)d_in[17];
  const float* proj_W   = (const float*)d_in[18];
  const float* proj_b   = (const float*)d_in[19];
  const float* lin_W    = (const float*)d_in[20];
  const float* lin_b    = (const float*)d_in[21];
  float* out = (float*)d_out;

  const int N = in_sizes[0] / 32;
  const int E = in_sizes[1] / 6;
  const int EN = E + N;
  const size_t NH = (size_t)N * 96;
  const int nh = (int)NH;
  const float inv_n = 1.f / (float)N;

  // ---- workspace layout (floats, then ints) ----
  float* f = (float*)d_ws;
  float* h_buf = f;  f += NH;
  float* pre   = f;  f += NH;        // aliased as wbuf (HGT phase A->B window)
  float* big   = f;  f += 9*NH;      // GAT: hp[3]; HGT: qKV[7] (q,K0..2,V0..2)
  float* aux   = f;  f += NH;        // injection | gelu(agg)
  float* asrc  = f;  f += (size_t)3*N*2;
  float* adst  = f;  f += (size_t)3*N*2;
  float* stats = f;  f += 6*192;     // 6 BN slots of (sum[96], sumsq[96])
  float* Wbig  = f;  f += 7*96*96;
  float* bbig  = f;  f += 7*96;
  int* ip = (int*)f;
  int* cnt     = ip;  ip += 4*N;
  int* rowptr  = ip;  ip += 4*(N+1);
  int* cursor  = ip;  ip += 4*N;
  int* idx_gat     = ip;  ip += 3*EN;
  int* idx_hgt     = ip;  ip += 3*E;
  int* idx_hgt_dst = ip;  ip += 3*E;
  float* wbuf = pre;                 // 3E*6 = 1.8M floats <= NH

  auto g1 = [](int n){ return dim3((n + TPB - 1)/TPB); };
  const int gx = (N + 95)/96;                 // GEMM row-tiles
  const dim3 gg(gx, 3);                       // 3-matrix GEMM grid
  const dim3 gg7(gx, 7);                      // 7-matrix HGT qKV grid
  const dim3 g1m(gx, 1);                      // 1-matrix GEMM grid
  const int cs_blocks = (nh + TPB*8 - 1)/(TPB*8);
  const int wave_blocks = (N + 3)/4;          // 4 waves (nodes) per 256-block

  // ---- CSR build + stats zero ----
  hipMemsetAsync(stats, 0, 6*192*sizeof(float), stream);
  k_init_cnt<<<g1(4*N),     TPB, 0, stream>>>(cnt, N);
  k_count   <<<g1(3*E),     TPB, 0, stream>>>(ei, cnt, N, E);
  k_scan4   <<<4,          1024, 0, stream>>>(cnt, rowptr, cursor, N);
  k_scatter <<<g1(3*E+3*N), TPB, 0, stream>>>(ei, cursor, idx_gat, idx_hgt, idx_hgt_dst, N, E);

  auto run_hgt = [&](int idx, int bnidx){
    k_prep     <<<g1(7*96*96 + 7*96), TPB, 0, stream>>>(
                   kqv_W + (size_t)idx*3*96*96, kqv_b + idx*3*96,
                   a_rel + (size_t)idx*3*6*256, m_rel + (size_t)idx*3*6*256,
                   p_rel + idx*18, Wbig, bbig);
    k_gemm_t   <<<gg7, GTPB, 0, stream>>>(h_buf, Wbig, bbig, big, N, 96);
    k_hgt_w    <<<g1(3*E*6), TPB, 0, stream>>>(big, big + NH, idx_hgt, idx_hgt_dst, wbuf, N, 3*E);
    k_hgt_fused<<<wave_blocks, TPB, 0, stream>>>(wbuf, big + 4*NH, rowptr, idx_hgt, aux, N);
    k_gemm_t   <<<g1m, GTPB, 0, stream>>>(aux, hout_W + (size_t)idx*96*96, hout_b + idx*96, pre, N, 96);
    k_mix_stats<<<cs_blocks, TPB, 0, stream>>>(pre, h_buf, skip + idx, stats + bnidx*192, nh);
    k_apply2   <<<g1(nh), TPB, 0, stream>>>(h_buf, pre, stats + bnidx*192,
                                            bn_g + bnidx*96, bn_b + bnidx*96, nullptr, 1, nh, inv_n);
  };

  // ---- GAT layer 0 (input dim 32, no residual) ----
  k_gemm_t   <<<gg, GTPB, 0, stream>>>(x, gat0_W, nullptr, big, N, 32);
  k_attdots  <<<g1(3*N), TPB, 0, stream>>>(big, gat0_att, asrc, adst, N);
  k_gat_fused<<<wave_blocks, TPB, 0, stream>>>(asrc, adst, big, rowptr, idx_gat, gat0_b, pre, N, EN);
  k_stats    <<<cs_blocks, TPB, 0, stream>>>(pre, stats, nh);
  k_apply2   <<<g1(nh), TPB, 0, stream>>>(h_buf, pre, stats, bn_g, bn_b, nullptr, 0, nh, inv_n);

  // ---- GAT layers 1..3 ----
  for (int i = 0; i < 3; i++){
    int li = i + 1;
    int bnidx = 1 + i;
    k_gemm_t   <<<gg, GTPB, 0, stream>>>(h_buf, gat_W + (size_t)i*3*96*96, nullptr, big, N, 96);
    k_attdots  <<<g1(3*N), TPB, 0, stream>>>(big, gat_att + i*3*192, asrc, adst, N);
    k_gat_fused<<<wave_blocks, TPB, 0, stream>>>(asrc, adst, big, rowptr, idx_gat,
                                                 gat_b + i*3*96, pre, N, EN);
    k_stats    <<<cs_blocks, TPB, 0, stream>>>(pre, stats + bnidx*192, nh);
    const float* inj = nullptr;
    if (li == 2 || li == 3){
      k_gemm_t<<<g1m, GTPB, 0, stream>>>(x, proj_W + (size_t)(li-2)*32*96, proj_b + (li-2)*96, aux, N, 32);
      inj = aux;
    }
    k_apply2<<<g1(nh), TPB, 0, stream>>>(h_buf, pre, stats + bnidx*192,
                                         bn_g + bnidx*96, bn_b + bnidx*96, inj, 1, nh, inv_n);
    if (li == 1) run_hgt(0, 4);
  }
  run_hgt(1, 5);

  k_final_lin<<<g1(N), TPB, 0, stream>>>(h_buf, lin_W, lin_b, out, N);
}

// Round 9
// 825.652 us; speedup vs baseline: 1.6088x; 1.1361x over previous
//
#include <hip/hip_runtime.h>
#include <math.h>

#define TPB 256

typedef __attribute__((ext_vector_type(8))) short short8;
typedef __attribute__((ext_vector_type(4))) float f32x4;

__device__ __forceinline__ float lrelu(float x){ return x > 0.f ? x : 0.2f*x; }
__device__ __forceinline__ unsigned short f2bf(float f){
  unsigned u = __float_as_uint(f);
  unsigned r = (u + 0x7FFF + ((u >> 16) & 1)) >> 16;   // RNE
  return (unsigned short)r;
}

// ---------------- CSR build (graph constant across layers) ----------------
__global__ void k_init_cnt(int* __restrict__ cnt, int N){
  int t = blockIdx.x*TPB + threadIdx.x;
  if (t < 4*N) cnt[t] = (t < 3*N) ? 1 : 0;  // GAT counts start at 1 (self-loop)
}

__global__ void k_count(const int* __restrict__ ei, int* __restrict__ cnt, int N, int E){
  int t = blockIdx.x*TPB + threadIdx.x;
  if (t >= 3*E) return;
  int r = t / E, e = t - r*E;
  int dst = ei[(r*2+1)*E + e];
  atomicAdd(&cnt[r*N + dst], 1);
  atomicAdd(&cnt[3*N + dst], 1);
}

// scan + cursor init fused
__global__ void k_scan4(const int* __restrict__ cnt, int* __restrict__ rp,
                        int* __restrict__ cur, int N){
  __shared__ int sh[1024];
  __shared__ int carry;
  int a = blockIdx.x;
  const int* c = cnt + a*N;
  int* r = rp + a*(N+1);
  if (threadIdx.x == 0) carry = 0;
  __syncthreads();
  for (int base = 0; base < N; base += 1024){
    int idx = base + threadIdx.x;
    int v = (idx < N) ? c[idx] : 0;
    sh[threadIdx.x] = v;
    __syncthreads();
    for (int off = 1; off < 1024; off <<= 1){
      int t = (threadIdx.x >= off) ? sh[threadIdx.x - off] : 0;
      __syncthreads();
      sh[threadIdx.x] += t;
      __syncthreads();
    }
    if (idx < N){
      int ex = carry + sh[threadIdx.x] - v;   // exclusive
      r[idx] = ex;
      cur[a*N + idx] = ex;
    }
    __syncthreads();
    if (threadIdx.x == 0) carry += sh[1023];
    __syncthreads();
  }
  if (threadIdx.x == 0) r[N] = carry;
}

__global__ void k_scatter(const int* __restrict__ ei, int* __restrict__ cur,
                          int* __restrict__ idx_gat,
                          int* __restrict__ idx_hgt, int* __restrict__ idx_hgt_dst,
                          int N, int E){
  int t = blockIdx.x*TPB + threadIdx.x;
  int EN = E + N;
  if (t < 3*E){
    int r = t / E, e = t - r*E;
    int src = ei[(r*2)*E + e];
    int dst = ei[(r*2+1)*E + e];
    int pg = atomicAdd(&cur[r*N + dst], 1);
    idx_gat[r*EN + pg] = src;
    int ph = atomicAdd(&cur[3*N + dst], 1);
    idx_hgt[ph] = r*N + src;           // packed (rel,src)
    idx_hgt_dst[ph] = dst;
  } else if (t < 3*E + 3*N){
    int tt = t - 3*E;
    int r = tt / N, i = tt - r*N;
    int pg = atomicAdd(&cur[r*N + i], 1);
    idx_gat[r*EN + pg] = i;            // self loop
  }
}

// ---------------- conversions: fp32 -> bf16 ----------------
__global__ void k_cvt(const float* __restrict__ in, unsigned short* __restrict__ out, int total){
  int t = blockIdx.x*TPB + threadIdx.x;
  if (t < total) out[t] = f2bf(in[t]);
}

// W [nmat][K][96] fp32 -> WT [nmat][96][K] bf16 (transposed for MFMA B-frag reads)
__global__ void k_cvtw(const float* __restrict__ W, unsigned short* __restrict__ WT,
                       int nmat, int K){
  int t = blockIdx.x*TPB + threadIdx.x;
  int total = nmat*96*K;
  if (t >= total) return;
  int m = t / (96*K);
  int rem = t - m*96*K;
  int o = rem / K;          // output col
  int c = rem - o*K;        // input k
  WT[t] = f2bf(W[((size_t)m*K + c)*96 + o]);
}

// ---------------- MFMA bf16 GEMM: C[mat] = A @ W[mat] (+ bias), fp32 out ----------------
// A: [n,K] bf16. WT: [nmat][96][K] bf16 (col-major-ish). Block: 4 waves x 32 rows = 128 rows.
__global__ __launch_bounds__(256) void k_gemm_mfma(
    const unsigned short* __restrict__ A, const unsigned short* __restrict__ WT,
    const float* __restrict__ bias, float* __restrict__ C, int n, int K){
  __shared__ unsigned short WlT[96*104];         // [col][K+8] padded: 2-way bank alias only
  const int Kp = K + 8;
  int mat = blockIdx.y;
  const unsigned short* Wm = WT + (size_t)mat*96*K;
  int chunks = 96*(K/8);
  for (int idx = threadIdx.x; idx < chunks; idx += 256){
    int col = idx/(K/8), kc = idx - col*(K/8);
    *reinterpret_cast<uint4*>(&WlT[col*Kp + kc*8]) =
      *reinterpret_cast<const uint4*>(&Wm[(size_t)col*K + kc*8]);
  }
  __syncthreads();

  int wave = threadIdx.x >> 6, lane = threadIdx.x & 63;
  int l15 = lane & 15, l4 = lane >> 4;
  int rowbase = blockIdx.x*128 + wave*32;

  f32x4 acc[2][6];
  #pragma unroll
  for (int rt = 0; rt < 2; rt++)
    #pragma unroll
    for (int ct = 0; ct < 6; ct++){
      f32x4 z = {0.f, 0.f, 0.f, 0.f};
      acc[rt][ct] = z;
    }

  for (int ks = 0; ks < K; ks += 32){
    short8 a[2];
    #pragma unroll
    for (int rt = 0; rt < 2; rt++){
      int row = rowbase + rt*16 + l15;
      if (row < n)
        a[rt] = *reinterpret_cast<const short8*>(A + (size_t)row*K + ks + l4*8);
      else {
        short8 z = {0,0,0,0,0,0,0,0};
        a[rt] = z;
      }
    }
    #pragma unroll
    for (int ct = 0; ct < 6; ct++){
      short8 b = *reinterpret_cast<const short8*>(&WlT[(ct*16 + l15)*Kp + ks + l4*8]);
      #pragma unroll
      for (int rt = 0; rt < 2; rt++)
        acc[rt][ct] = __builtin_amdgcn_mfma_f32_16x16x32_bf16(a[rt], b, acc[rt][ct], 0, 0, 0);
    }
  }

  // C/D layout (m89): col = lane&15, row = (lane>>4)*4 + reg
  #pragma unroll
  for (int rt = 0; rt < 2; rt++){
    #pragma unroll
    for (int ct = 0; ct < 6; ct++){
      int col = ct*16 + l15;
      float bv = bias ? bias[mat*96 + col] : 0.f;
      #pragma unroll
      for (int r = 0; r < 4; r++){
        int row = rowbase + rt*16 + l4*4 + r;
        if (row < n)
          C[(size_t)mat*n*96 + (size_t)row*96 + col] = acc[rt][ct][r] + bv;
      }
    }
  }
}

// ---------------- fp32 LDS-tiled GEMM (kept for hout: A is fp32 aux) ----------------
#define GTPB 384
__global__ __launch_bounds__(GTPB) void k_gemm_t(const float* __restrict__ A,
                        const float* __restrict__ W,
                        const float* __restrict__ bias, float* __restrict__ C,
                        int n, int K){
  __shared__ float Wl[96*96];
  int mat = blockIdx.y;
  const float4* Wm4 = reinterpret_cast<const float4*>(W + (size_t)mat*K*96);
  for (int idx = threadIdx.x; idx < K*24; idx += GTPB)
    reinterpret_cast<float4*>(Wl)[idx] = Wm4[idx];
  __syncthreads();

  int cg = threadIdx.x % 12;
  int rg = threadIdx.x / 12;
  int c0 = cg*8;
  int r0 = blockIdx.x*96 + rg*3;

  float acc[3][8];
  #pragma unroll
  for (int u = 0; u < 3; u++)
    #pragma unroll
    for (int c = 0; c < 8; c++) acc[u][c] = 0.f;

  for (int k = 0; k < K; k += 4){
    float4 a[3];
    #pragma unroll
    for (int u = 0; u < 3; u++){
      int r = r0 + u;
      a[u] = (r < n) ? *reinterpret_cast<const float4*>(A + (size_t)r*K + k)
                     : make_float4(0.f,0.f,0.f,0.f);
    }
    #pragma unroll
    for (int kk = 0; kk < 4; kk++){
      float4 w0 = *reinterpret_cast<const float4*>(Wl + (k+kk)*96 + c0);
      float4 w1 = *reinterpret_cast<const float4*>(Wl + (k+kk)*96 + c0 + 4);
      float wv0 = w0.x, wv1 = w0.y, wv2 = w0.z, wv3 = w0.w;
      float wv4 = w1.x, wv5 = w1.y, wv6 = w1.z, wv7 = w1.w;
      #pragma unroll
      for (int u = 0; u < 3; u++){
        float av = (kk==0) ? a[u].x : (kk==1) ? a[u].y : (kk==2) ? a[u].z : a[u].w;
        acc[u][0] += av*wv0; acc[u][1] += av*wv1; acc[u][2] += av*wv2; acc[u][3] += av*wv3;
        acc[u][4] += av*wv4; acc[u][5] += av*wv5; acc[u][6] += av*wv6; acc[u][7] += av*wv7;
      }
    }
  }

  float b[8];
  if (bias){
    const float* bp = bias + mat*96 + c0;
    #pragma unroll
    for (int c = 0; c < 8; c++) b[c] = bp[c];
  } else {
    #pragma unroll
    for (int c = 0; c < 8; c++) b[c] = 0.f;
  }
  #pragma unroll
  for (int u = 0; u < 3; u++){
    int r = r0 + u;
    if (r < n){
      float* Cr = C + (size_t)mat*n*96 + (size_t)r*96 + c0;
      float4 o0 = make_float4(acc[u][0]+b[0], acc[u][1]+b[1], acc[u][2]+b[2], acc[u][3]+b[3]);
      float4 o1 = make_float4(acc[u][4]+b[4], acc[u][5]+b[5], acc[u][6]+b[6], acc[u][7]+b[7]);
      reinterpret_cast<float4*>(Cr)[0] = o0;
      reinterpret_cast<float4*>(Cr)[1] = o1;
    }
  }
}

// ---------------- HGT effective-weight prep -> bf16 transposed Wbig + fp32 bias ----------
// WbigT[7][96out][96in] bf16: mat0=q, mat1..3=K_r (x 0.25*p_rel), mat4..6=V_r.
__global__ void k_prep(const float* __restrict__ kW, const float* __restrict__ kb,
                       const float* __restrict__ arel, const float* __restrict__ mrel,
                       const float* __restrict__ prel,
                       unsigned short* __restrict__ WbigT, float* __restrict__ bbig){
  int t = blockIdx.x*TPB + threadIdx.x;
  const int total = 7*96*96;
  if (t < total){
    int m = t / (96*96);
    int rem = t - m*(96*96);
    int o = rem / 96;        // output col
    int c = rem - o*96;      // input k
    float val;
    if (m == 0){
      val = kW[(size_t)96*96 + c*96 + o];            // q weights
    } else {
      int r = (m - 1) % 3;
      bool isV = m >= 4;
      const float* base = isV ? mrel : arel;         // [3][6][16][16]
      const float* wsrc = kW + (size_t)(isV ? 2 : 0)*96*96;
      int h = o >> 4, ff = o & 15;
      float s = 0.f;
      #pragma unroll
      for (int d = 0; d < 16; d++)
        s += wsrc[c*96 + h*16 + d] * base[(size_t)((r*6 + h)*16 + d)*16 + ff];
      if (!isV) s *= 0.25f * prel[r*6 + h];
      val = s;
    }
    WbigT[t] = f2bf(val);    // t == (m*96 + o)*96 + c
  } else if (t < total + 7*96){
    int tt = t - total;
    int m = tt / 96, o = tt - m*96;
    float val;
    if (m == 0){
      val = kb[96 + o];
    } else {
      int r = (m - 1) % 3;
      bool isV = m >= 4;
      const float* base = isV ? mrel : arel;
      const float* bsrc = kb + (isV ? 2 : 0)*96;
      int h = o >> 4, ff = o & 15;
      float s = 0.f;
      #pragma unroll
      for (int d = 0; d < 16; d++)
        s += bsrc[h*16 + d] * base[(size_t)((r*6 + h)*16 + d)*16 + ff];
      if (!isV) s *= 0.25f * prel[r*6 + h];
      val = s;
    }
    bbig[tt] = val;
  }
}

// ---------------- GAT attention dots: a_src/a_dst [3,N,2] ----------------
__global__ void k_attdots(const float* __restrict__ hp, const float* __restrict__ att,
                          float* __restrict__ asrc, float* __restrict__ adst, int n){
  int t = blockIdx.x*TPB + threadIdx.x;
  if (t >= 3*n) return;
  int r = t / n;                       // t == r*n+i
  const float* row = hp + (size_t)t*96;
  const float* ap  = att + r*192;      // [2,2,48] per relation
  #pragma unroll
  for (int h = 0; h < 2; h++){
    float s = 0.f, d = 0.f;
    #pragma unroll 8
    for (int dd = 0; dd < 48; dd++){
      float v = row[h*48 + dd];
      s += v * ap[h*48 + dd];
      d += v * ap[96 + h*48 + dd];
    }
    asrc[t*2 + h] = s;
    adst[t*2 + h] = d;
  }
}

// ---------------- GAT fused: wave per node; 3 relations; weights + gather + combine + bias ----
__global__ __launch_bounds__(TPB) void k_gat_fused(const float* __restrict__ asrc,
                        const float* __restrict__ adst, const float* __restrict__ hp,
                        const int* __restrict__ rowptr, const int* __restrict__ idxg,
                        const float* __restrict__ b3, float* __restrict__ pre,
                        int n, int EN){
  int wid = (blockIdx.x*TPB + threadIdx.x) >> 6;   // wave id = node
  if (wid >= n) return;
  int lane = threadIdx.x & 63;
  float comb_a = 0.f, comb_b = 0.f;
  #pragma unroll
  for (int r = 0; r < 3; r++){
    const int* rp = rowptr + r*(n+1);
    int s0 = rp[wid], s1 = rp[wid+1];
    const int* ix = idxg + (size_t)r*EN;
    const float2* as2 = reinterpret_cast<const float2*>(asrc) + (size_t)r*n;
    float2 ad = (reinterpret_cast<const float2*>(adst) + (size_t)r*n)[wid];
    const float* hpb = hp + (size_t)r*n*96;
    float acc_a = 0.f, acc_b = 0.f, ss0 = 0.f, ss1 = 0.f;
    for (int base = s0; base < s1; base += 64){
      int cnt = min(64, s1 - base);
      int src_l = 0; float w0_l = 0.f, w1_l = 0.f;
      if (lane < cnt){
        src_l = ix[base + lane];
        float2 av = as2[src_l];
        w0_l = __expf(fminf(lrelu(av.x + ad.x), 80.f));
        w1_l = __expf(fminf(lrelu(av.y + ad.y), 80.f));
      }
      for (int j = 0; j < cnt; j++){
        int   src = __shfl(src_l, j);
        float w0  = __shfl(w0_l, j);
        float w1  = __shfl(w1_l, j);
        const float* row = hpb + (size_t)src*96;
        float va = row[lane];
        float vb = (lane < 32) ? row[64 + lane] : 0.f;
        float wa = (lane < 48) ? w0 : w1;
        acc_a += wa*va;
        acc_b += w1*vb;
        ss0 += w0; ss1 += w1;
      }
    }
    comb_a += acc_a / ((lane < 48) ? ss0 : ss1);   // self-loop => non-empty
    comb_b += acc_b / ss1;
  }
  comb_a += b3[lane] + b3[96 + lane] + b3[192 + lane];
  float* pr = pre + (size_t)wid*96;
  pr[lane] = comb_a;
  if (lane < 32){
    comb_b += b3[64 + lane] + b3[160 + lane] + b3[256 + lane];
    pr[64 + lane] = comb_b;
  }
}

// ---------------- BN stats over pre: grid-stride sum/sumsq ----------------
__global__ void k_stats(const float* __restrict__ pre, float* __restrict__ stats, int total){
  __shared__ float s1[96], s2[96];
  if (threadIdx.x < 96){ s1[threadIdx.x] = 0.f; s2[threadIdx.x] = 0.f; }
  __syncthreads();
  int idx0 = blockIdx.x*TPB*8 + threadIdx.x;
  for (int it = 0; it < 8; it++){
    int idx = idx0 + it*TPB;
    if (idx < total){
      int c = idx % 96;
      float v = pre[idx];
      atomicAdd(&s1[c], v);
      atomicAdd(&s2[c], v*v);
    }
  }
  __syncthreads();
  if (threadIdx.x < 96){
    atomicAdd(&stats[threadIdx.x], s1[threadIdx.x]);
    atomicAdd(&stats[96 + threadIdx.x], s2[threadIdx.x]);
  }
}

// ---------------- HGT skip-mix in place + BN stats ----------------
__global__ void k_mix_stats(float* __restrict__ pre, const float* __restrict__ h,
                            const float* __restrict__ skip, float* __restrict__ stats, int total){
  __shared__ float s1[96], s2[96];
  if (threadIdx.x < 96){ s1[threadIdx.x] = 0.f; s2[threadIdx.x] = 0.f; }
  __syncthreads();
  float sk = 1.f / (1.f + expf(-skip[0]));
  int idx0 = blockIdx.x*TPB*8 + threadIdx.x;
  for (int it = 0; it < 8; it++){
    int idx = idx0 + it*TPB;
    if (idx < total){
      int c = idx % 96;
      float v = sk*pre[idx] + (1.f - sk)*h[idx];
      pre[idx] = v;
      atomicAdd(&s1[c], v);
      atomicAdd(&s2[c], v*v);
    }
  }
  __syncthreads();
  if (threadIdx.x < 96){
    atomicAdd(&stats[threadIdx.x], s1[threadIdx.x]);
    atomicAdd(&stats[96 + threadIdx.x], s2[threadIdx.x]);
  }
}

// ---------------- apply with inline BN finalize; writes fp32 h AND bf16 h ----------------
__global__ void k_apply2(float* __restrict__ h, unsigned short* __restrict__ hb,
                         const float* __restrict__ pre,
                         const float* __restrict__ stats, const float* __restrict__ gamma,
                         const float* __restrict__ beta, const float* __restrict__ inj,
                         int res, int total, float inv_n){
  int idx = blockIdx.x*TPB + threadIdx.x;
  if (idx >= total) return;
  int c = idx % 96;
  float mean = stats[c] * inv_n;
  float var  = stats[96 + c] * inv_n - mean*mean;
  float sc   = gamma[c] * rsqrtf(var + 1e-5f);
  float sh   = beta[c] - mean*sc;
  float v = sc*pre[idx] + sh;
  if (inj) v += inj[idx];
  if (res) v += h[idx];
  v = lrelu(v);
  h[idx] = v;
  hb[idx] = f2bf(v);
}

// ---------------- HGT phase A: per-(slot,head) edge weights (scale pre-folded) ----------------
__global__ void k_hgt_w(const float* __restrict__ q, const float* __restrict__ Kb,
                        const int* __restrict__ idxh, const int* __restrict__ idxh_dst,
                        float* __restrict__ wbuf, int n, int totE){
  int t = blockIdx.x*TPB + threadIdx.x;
  if (t >= totE*6) return;
  int slot = t / 6, h = t - slot*6;
  int packed = idxh[slot];
  int dst = idxh_dst[slot];
  const float4* kp = reinterpret_cast<const float4*>(Kb + (size_t)packed*96 + h*16);
  const float4* qp = reinterpret_cast<const float4*>(q + (size_t)dst*96 + h*16);
  float dot = 0.f;
  #pragma unroll
  for (int w = 0; w < 4; w++){
    float4 kv = kp[w], qv = qp[w];
    dot += kv.x*qv.x + kv.y*qv.y + kv.z*qv.z + kv.w*qv.w;
  }
  wbuf[t] = __expf(fminf(dot, 80.f));
}

// ---------------- HGT fused gather: wave per node; shfl-staged; + GELU ----------------
__global__ __launch_bounds__(TPB) void k_hgt_fused(const float* __restrict__ wbuf,
                        const float* __restrict__ Vb, const int* __restrict__ rp4,
                        const int* __restrict__ idxh, float* __restrict__ gbuf, int n){
  int wid = (blockIdx.x*TPB + threadIdx.x) >> 6;
  if (wid >= n) return;
  int lane = threadIdx.x & 63;
  const int* rp = rp4 + 3*(n+1);
  int s0 = rp[wid], s1 = rp[wid+1];
  int ha = lane >> 4;                         // head for col=lane (0..3)
  float acc_a = 0.f, acc_b = 0.f, ss_a = 0.f, ss_b = 0.f;
  for (int base = s0; base < s1; base += 64){
    int cnt = min(64, s1 - base);
    int pk = 0; float w0=0.f,w1=0.f,w2=0.f,w3=0.f,w4=0.f,w5=0.f;
    if (lane < cnt){
      int slot = base + lane;
      pk = idxh[slot];
      const float2* wp = reinterpret_cast<const float2*>(wbuf + (size_t)slot*6);
      float2 p0 = wp[0], p1 = wp[1], p2 = wp[2];
      w0=p0.x; w1=p0.y; w2=p1.x; w3=p1.y; w4=p2.x; w5=p2.y;
    }
    for (int j = 0; j < cnt; j++){
      int packed = __shfl(pk, j);
      float b0=__shfl(w0,j), b1=__shfl(w1,j), b2=__shfl(w2,j),
            b3v=__shfl(w3,j), b4=__shfl(w4,j), b5=__shfl(w5,j);
      const float* row = Vb + (size_t)packed*96;
      float va = row[lane];
      float vb = (lane < 32) ? row[64 + lane] : 0.f;
      float wa = (ha==0) ? b0 : ((ha==1) ? b1 : ((ha==2) ? b2 : b3v));
      float wb = ((lane >> 4) == 0) ? b4 : b5;   // head 4/5 for cols 64..95
      acc_a += wa*va; ss_a += wa;
      acc_b += wb*vb; ss_b += wb;
    }
  }
  float xa = (s1 > s0) ? acc_a/ss_a : 0.f;
  float* gb = gbuf + (size_t)wid*96;
  gb[lane] = 0.5f*xa*(1.f + erff(xa*0.70710678118654752f));
  if (lane < 32){
    float xb = (s1 > s0) ? acc_b/ss_b : 0.f;
    gb[64 + lane] = 0.5f*xb*(1.f + erff(xb*0.70710678118654752f));
  }
}

// ---------------- final linear ----------------
__global__ void k_final_lin(const float* __restrict__ h, const float* __restrict__ w,
                            const float* __restrict__ b, float* __restrict__ out, int N){
  int i = blockIdx.x*TPB + threadIdx.x;
  if (i >= N) return;
  const float4* hr = reinterpret_cast<const float4*>(h + (size_t)i*96);
  const float4* wr = reinterpret_cast<const float4*>(w);
  float acc = 0.f;
  #pragma unroll
  for (int c = 0; c < 24; c++){
    float4 a = hr[c], q = wr[c];
    acc += a.x*q.x + a.y*q.y + a.z*q.z + a.w*q.w;
  }
  out[i] = acc + b[0];
}

// =====================================================================
extern "C" void kernel_launch(void* const* d_in, const int* in_sizes, int n_in,
                              void* d_out, int out_size, void* d_ws, size_t ws_size,
                              hipStream_t stream){
  const float* x        = (const float*)d_in[0];
  const int*   ei       = (const int*)  d_in[1];
  const float* gat0_W   = (const float*)d_in[2];
  const float* gat0_att = (const float*)d_in[3];
  const float* gat0_b   = (const float*)d_in[4];
  const float* gat_W    = (const float*)d_in[5];
  const float* gat_att  = (const float*)d_in[6];
  const float* gat_b    = (const float*)d_in[7];
  const float* bn_g     = (const float*)d_in[8];
  const float* bn_b     = (const float*)d_in[9];
  const float* kqv_W    = (const float*)d_in[10];
  const float* kqv_b    = (const float*)d_in[11];
  const float* a_rel    = (const float*)d_in[12];
  const float* m_rel    = (const float*)d_in[13];
  const float* p_rel    = (const float*)d_in[14];
  const float* hout_W   = (const float*)d_in[15];
  const float* hout_b   = (const float*)d_in[16];
  const float* skip     = (const float*)d_in[17];
  const float* proj_W   = (const float*)d_in[18];
  const float* proj_b   = (const float*)d_in[19];
  const float* lin_W    = (const float*)d_in[20];
  const float* lin_b    = (const float*)d_in[21];
  float* out = (float*)d_out;

  const int N = in_sizes[0] / 32;
  const int E = in_sizes[1] / 6;
  const int EN = E + N;
  const size_t NH = (size_t)N * 96;
  const int nh = (int)NH;
  const float inv_n = 1.f / (float)N;

  // ---- workspace layout (floats, then bf16, then ints) ----
  float* f = (float*)d_ws;
  float* h_buf = f;  f += NH;
  float* pre   = f;  f += NH;        // aliased as wbuf (HGT phase A->B window)
  float* big   = f;  f += 9*NH;      // GAT: hp[3]; HGT: qKV[7] (q,K0..2,V0..2)
  float* aux   = f;  f += NH;        // injection | gelu(agg)
  float* asrc  = f;  f += (size_t)3*N*2;
  float* adst  = f;  f += (size_t)3*N*2;
  float* stats = f;  f += 6*192;     // 6 BN slots of (sum[96], sumsq[96])
  float* bbig  = f;  f += 7*96;
  unsigned short* us = (unsigned short*)f;
  unsigned short* hb     = us;  us += NH;          // bf16 h
  unsigned short* xb     = us;  us += (size_t)N*32;
  unsigned short* WbigT  = us;  us += 7*96*96;
  unsigned short* Wgat0T = us;  us += 3*96*32;
  unsigned short* WgatT  = us;  us += 9*96*96;
  unsigned short* WprojT = us;  us += 2*96*32;
  us += (us - (unsigned short*)f) & 1;             // realign to 4B
  int* ip = (int*)us;
  int* cnt     = ip;  ip += 4*N;
  int* rowptr  = ip;  ip += 4*(N+1);
  int* cursor  = ip;  ip += 4*N;
  int* idx_gat     = ip;  ip += 3*EN;
  int* idx_hgt     = ip;  ip += 3*E;
  int* idx_hgt_dst = ip;  ip += 3*E;
  float* wbuf = pre;                 // 3E*6 = 1.8M floats <= NH

  auto g1 = [](int n){ return dim3((n + TPB - 1)/TPB); };
  const int gx  = (N + 95)/96;                // fp32 GEMM row-tiles
  const int gx2 = (N + 127)/128;              // MFMA GEMM row-tiles
  const dim3 mg3(gx2, 3);                     // 3-mat MFMA grid (GAT)
  const dim3 mg7(gx2, 7);                     // 7-mat MFMA grid (HGT qKV)
  const dim3 mg1(gx2, 1);
  const dim3 g1m(gx, 1);                      // fp32 1-mat GEMM grid (hout)
  const int cs_blocks = (nh + TPB*8 - 1)/(TPB*8);
  const int wave_blocks = (N + 3)/4;          // 4 waves (nodes) per 256-block

  // ---- CSR build + stats zero + one-time conversions ----
  hipMemsetAsync(stats, 0, 6*192*sizeof(float), stream);
  k_init_cnt<<<g1(4*N),     TPB, 0, stream>>>(cnt, N);
  k_count   <<<g1(3*E),     TPB, 0, stream>>>(ei, cnt, N, E);
  k_scan4   <<<4,          1024, 0, stream>>>(cnt, rowptr, cursor, N);
  k_scatter <<<g1(3*E+3*N), TPB, 0, stream>>>(ei, cursor, idx_gat, idx_hgt, idx_hgt_dst, N, E);
  k_cvt     <<<g1(N*32),    TPB, 0, stream>>>(x, xb, N*32);
  k_cvtw    <<<g1(3*96*32), TPB, 0, stream>>>(gat0_W, Wgat0T, 3, 32);
  k_cvtw    <<<g1(9*96*96), TPB, 0, stream>>>(gat_W,  WgatT,  9, 96);
  k_cvtw    <<<g1(2*96*32), TPB, 0, stream>>>(proj_W, WprojT, 2, 32);

  auto run_hgt = [&](int idx, int bnidx){
    k_prep     <<<g1(7*96*96 + 7*96), TPB, 0, stream>>>(
                   kqv_W + (size_t)idx*3*96*96, kqv_b + idx*3*96,
                   a_rel + (size_t)idx*3*6*256, m_rel + (size_t)idx*3*6*256,
                   p_rel + idx*18, WbigT, bbig);
    k_gemm_mfma<<<mg7, 256, 0, stream>>>(hb, WbigT, bbig, big, N, 96);
    k_hgt_w    <<<g1(3*E*6), TPB, 0, stream>>>(big, big + NH, idx_hgt, idx_hgt_dst, wbuf, N, 3*E);
    k_hgt_fused<<<wave_blocks, TPB, 0, stream>>>(wbuf, big + 4*NH, rowptr, idx_hgt, aux, N);
    k_gemm_t   <<<g1m, GTPB, 0, stream>>>(aux, hout_W + (size_t)idx*96*96, hout_b + idx*96, pre, N, 96);
    k_mix_stats<<<cs_blocks, TPB, 0, stream>>>(pre, h_buf, skip + idx, stats + bnidx*192, nh);
    k_apply2   <<<g1(nh), TPB, 0, stream>>>(h_buf, hb, pre, stats + bnidx*192,
                                            bn_g + bnidx*96, bn_b + bnidx*96, nullptr, 1, nh, inv_n);
  };

  // ---- GAT layer 0 (input dim 32, no residual) ----
  k_gemm_mfma<<<mg3, 256, 0, stream>>>(xb, Wgat0T, nullptr, big, N, 32);
  k_attdots  <<<g1(3*N), TPB, 0, stream>>>(big, gat0_att, asrc, adst, N);
  k_gat_fused<<<wave_blocks, TPB, 0, stream>>>(asrc, adst, big, rowptr, idx_gat, gat0_b, pre, N, EN);
  k_stats    <<<cs_blocks, TPB, 0, stream>>>(pre, stats, nh);
  k_apply2   <<<g1(nh), TPB, 0, stream>>>(h_buf, hb, pre, stats, bn_g, bn_b, nullptr, 0, nh, inv_n);

  // ---- GAT layers 1..3 ----
  for (int i = 0; i < 3; i++){
    int li = i + 1;
    int bnidx = 1 + i;
    k_gemm_mfma<<<mg3, 256, 0, stream>>>(hb, WgatT + (size_t)i*3*96*96, nullptr, big, N, 96);
    k_attdots  <<<g1(3*N), TPB, 0, stream>>>(big, gat_att + i*3*192, asrc, adst, N);
    k_gat_fused<<<wave_blocks, TPB, 0, stream>>>(asrc, adst, big, rowptr, idx_gat,
                                                 gat_b + i*3*96, pre, N, EN);
    k_stats    <<<cs_blocks, TPB, 0, stream>>>(pre, stats + bnidx*192, nh);
    const float* inj = nullptr;
    if (li == 2 || li == 3){
      k_gemm_mfma<<<mg1, 256, 0, stream>>>(xb, WprojT + (size_t)(li-2)*96*32,
                                           proj_b + (li-2)*96, aux, N, 32);
      inj = aux;
    }
    k_apply2<<<g1(nh), TPB, 0, stream>>>(h_buf, hb, pre, stats + bnidx*192,
                                         bn_g + bnidx*96, bn_b + bnidx*96, inj, 1, nh, inv_n);
    if (li == 1) run_hgt(0, 4);
  }
  run_hgt(1, 5);

  k_final_lin<<<g1(N), TPB, 0, stream>>>(h_buf, lin_W, lin_b, out, N);
}